// Round 4
// baseline (4144.832 us; speedup 1.0000x reference)
//
#include <hip/hip_runtime.h>
#include <cstddef>

#define NT 100000
#define NN1 40000
#define NN2 30000
#define NN3 30000
#define EE 800000
#define DIN 256
#define DHID 256   // 2 * out_channels = 256 (NOT 512 — R2/R3 bug)
#define DOUT 128

static inline int cdiv(int a, int b) { return (a + b - 1) / b; }

__global__ void k_init_deg(float* __restrict__ deg, int n) {
    int i = blockIdx.x * blockDim.x + threadIdx.x;
    if (i < n) deg[i] = 1.0f;
}

__global__ void k_deg_scatter(const int* __restrict__ dst, float* __restrict__ deg, int e) {
    int i = blockIdx.x * blockDim.x + threadIdx.x;
    if (i < e) atomicAdd(&deg[dst[i]], 1.0f);
}

__global__ void k_rsqrt(float* __restrict__ deg, int n) {
    int i = blockIdx.x * blockDim.x + threadIdx.x;
    if (i < n) deg[i] = rsqrtf(deg[i]);
}

// C[M,N] = op(A[M,K]) @ B[K,N] (+ bias). op = relu if RELU_A.
// 64x64 tile, BK=16, 256 threads, 4x4 micro-tile per thread.
// Requires: K % 16 == 0, N % 64 == 0. M arbitrary (guarded).
template<bool RELU_A>
__global__ void k_sgemm(const float* __restrict__ A, const float* __restrict__ B,
                        const float* __restrict__ bias, float* __restrict__ C,
                        int M, int K, int N) {
    __shared__ float As[16][65];  // [k][m]
    __shared__ float Bs[16][65];  // [k][n]
    const int bm = blockIdx.x * 64;
    const int bn = blockIdx.y * 64;
    const int tid = threadIdx.x;
    const int tx = tid & 15;       // n-group
    const int ty = tid >> 4;       // m-group

    float acc[4][4] = {};

    for (int k0 = 0; k0 < K; k0 += 16) {
        #pragma unroll
        for (int i = tid; i < 64 * 16; i += 256) {
            int r = i >> 4, c = i & 15;
            float v = 0.f;
            if (bm + r < M) {
                v = A[(size_t)(bm + r) * K + (k0 + c)];
                if (RELU_A) v = fmaxf(v, 0.f);
            }
            As[c][r] = v;
        }
        #pragma unroll
        for (int i = tid; i < 16 * 64; i += 256) {
            int kk = i >> 6, c = i & 63;
            Bs[kk][c] = B[(size_t)(k0 + kk) * N + (bn + c)];
        }
        __syncthreads();
        #pragma unroll
        for (int kk = 0; kk < 16; ++kk) {
            float a[4], b[4];
            #pragma unroll
            for (int i = 0; i < 4; ++i) a[i] = As[kk][ty * 4 + i];
            #pragma unroll
            for (int j = 0; j < 4; ++j) b[j] = Bs[kk][tx * 4 + j];
            #pragma unroll
            for (int i = 0; i < 4; ++i)
                #pragma unroll
                for (int j = 0; j < 4; ++j) acc[i][j] += a[i] * b[j];
        }
        __syncthreads();
    }

    #pragma unroll
    for (int i = 0; i < 4; ++i) {
        int r = bm + ty * 4 + i;
        if (r < M) {
            #pragma unroll
            for (int j = 0; j < 4; ++j) {
                int c = bn + tx * 4 + j;
                float v = acc[i][j];
                if (bias) v += bias[c];
                C[(size_t)r * N + c] = v;
            }
        }
    }
}

// agg[j][d] = f[j][d] * dis[j]^2 (+ bias[d])   (self-loop init)
template<int D>
__global__ void k_agg_init(const float* __restrict__ f, const float* __restrict__ dis,
                           const float* __restrict__ bias, float* __restrict__ agg, int n) {
    long long idx = (long long)blockIdx.x * blockDim.x + threadIdx.x;
    if (idx >= (long long)n * D) return;
    int row = (int)(idx / D);
    int col = (int)(idx & (D - 1));
    float dd = dis[row];
    float v = f[idx] * (dd * dd);
    if (bias) v += bias[col];
    agg[idx] = v;
}

// one wave (64 lanes) per edge: agg[dst] += f[src] * dis[src]*dis[dst]
template<int D>
__global__ void k_edge_scatter(const float* __restrict__ f, const float* __restrict__ dis,
                               const int* __restrict__ src, const int* __restrict__ dst,
                               float* __restrict__ agg, int e) {
    int wave = (int)(((long long)blockIdx.x * blockDim.x + threadIdx.x) >> 6);
    int lane = threadIdx.x & 63;
    if (wave >= e) return;
    int s = src[wave];
    int t = dst[wave];
    float w = dis[s] * dis[t];
    const float* fs = f + (size_t)s * D;
    float* at = agg + (size_t)t * D;
    if constexpr (D == 256) {
        float4 v = reinterpret_cast<const float4*>(fs)[lane];
        int off = lane * 4;
        atomicAdd(at + off + 0, v.x * w);
        atomicAdd(at + off + 1, v.y * w);
        atomicAdd(at + off + 2, v.z * w);
        atomicAdd(at + off + 3, v.w * w);
    } else {
        // D == 128: 2 floats per lane
        float2 v = reinterpret_cast<const float2*>(fs)[lane];
        atomicAdd(at + lane * 2 + 0, v.x * w);
        atomicAdd(at + lane * 2 + 1, v.y * w);
    }
}

extern "C" void kernel_launch(void* const* d_in, const int* in_sizes, int n_in,
                              void* d_out, int out_size, void* d_ws, size_t ws_size,
                              hipStream_t stream) {
    const float* x1  = (const float*)d_in[0];
    const float* x2  = (const float*)d_in[1];
    const float* x3  = (const float*)d_in[2];
    const float* Wp1 = (const float*)d_in[3];
    const float* bp1 = (const float*)d_in[4];
    const float* Wp2 = (const float*)d_in[5];
    const float* bp2 = (const float*)d_in[6];
    const float* Wp3 = (const float*)d_in[7];
    const float* bp3 = (const float*)d_in[8];
    const float* W1  = (const float*)d_in[9];   // (256, 256)
    const float* b1  = (const float*)d_in[10];  // (256,)
    const float* W2  = (const float*)d_in[11];  // (256, 128)
    const float* b2  = (const float*)d_in[12];  // (128,)
    const int*   ei  = (const int*)d_in[13];    // int32 (proven: R2==R3 output)
    const int* src = ei;
    const int* dst = ei + EE;
    float* out = (float*)d_out;

    // workspace layout (~205.6 MB), 512B-aligned slots
    char* ws = (char*)d_ws;
    size_t off = 0;
    auto alloc = [&](size_t bytes) {
        char* p = ws + off;
        off += (bytes + 511) & ~(size_t)511;
        return p;
    };
    float* dis   = (float*)alloc((size_t)NT * 4);          // 0.4 MB
    float* slotA = (float*)alloc((size_t)NT * DIN * 4);    // 102.4 MB: x, then h
    float* slotB = (float*)alloc((size_t)NT * DIN * 4);    // 102.4 MB: aggX, then hW2

    float* x    = slotA;   // phase 2-3
    float* aggX = slotB;   // phase 3-4
    float* h    = slotA;   // phase 4-5 (overwrites dead x)
    float* hW2  = slotB;   // phase 5-6 (overwrites dead aggX; 51.2 MB)

    // 1) degree -> dis
    k_init_deg<<<cdiv(NT, 256), 256, 0, stream>>>(dis, NT);
    k_deg_scatter<<<cdiv(EE, 256), 256, 0, stream>>>(dst, dis, EE);
    k_rsqrt<<<cdiv(NT, 256), 256, 0, stream>>>(dis, NT);

    // 2) per-type projections into x
    {
        dim3 g1(cdiv(NN1, 64), DIN / 64);
        k_sgemm<false><<<g1, 256, 0, stream>>>(x1, Wp1, bp1, x, NN1, 128, DIN);
        dim3 g2(cdiv(NN2, 64), DIN / 64);
        k_sgemm<false><<<g2, 256, 0, stream>>>(x2, Wp2, bp2, x + (size_t)NN1 * DIN, NN2, 256, DIN);
        dim3 g3(cdiv(NN3, 64), DIN / 64);
        k_sgemm<false><<<g3, 256, 0, stream>>>(x3, Wp3, bp3, x + (size_t)(NN1 + NN2) * DIN, NN3, 64, DIN);
    }

    // 3) aggX = Â x   (aggregate BEFORE W1: Â(XW1) = (ÂX)W1 by linearity)
    k_agg_init<DIN><<<NT * DIN / 256, 256, 0, stream>>>(x, dis, nullptr, aggX, NT);
    k_edge_scatter<DIN><<<EE / 4, 256, 0, stream>>>(x, dis, src, dst, aggX, EE);

    // 4) h = aggX @ W1 + b1   [NT,256] (relu deferred to next GEMM's A-load)
    {
        dim3 g(cdiv(NT, 64), DHID / 64);
        k_sgemm<false><<<g, 256, 0, stream>>>(aggX, W1, b1, h, NT, DIN, DHID);
    }

    // 5) hW2 = relu(h) @ W2   [NT,128]
    {
        dim3 g(cdiv(NT, 64), DOUT / 64);
        k_sgemm<true><<<g, 256, 0, stream>>>(h, W2, nullptr, hW2, NT, DHID, DOUT);
    }

    // 6) out = Â hW2 + b2
    k_agg_init<DOUT><<<NT * DOUT / 256, 256, 0, stream>>>(hW2, dis, b2, out, NT);
    k_edge_scatter<DOUT><<<EE / 4, 256, 0, stream>>>(hW2, dis, src, dst, out, EE);
}

// Round 5
// 979.083 us; speedup vs baseline: 4.2334x; 4.2334x over previous
//
#include <hip/hip_runtime.h>
#include <cstddef>

#define NT 100000
#define NN1 40000
#define NN2 30000
#define NN3 30000
#define EE 800000
#define DIN 256
#define DHID 256   // 2 * out_channels = 256
#define DOUT 128

static inline int cdiv(int a, int b) { return (a + b - 1) / b; }

// ---------------- CSR build (dst-sorted adjacency), all on-device ----------
__global__ void k_zero_i32(int* __restrict__ p, int n) {
    int i = blockIdx.x * blockDim.x + threadIdx.x;
    if (i < n) p[i] = 0;
}

__global__ void k_hist(const int* __restrict__ dst, int* __restrict__ cnt, int e) {
    int i = blockIdx.x * blockDim.x + threadIdx.x;
    if (i < e) atomicAdd(&cnt[dst[i]], 1);
}

// dis[i] = rsqrt(1 + in_degree)   (self-loop included, as in gcn_norm)
__global__ void k_dis(const int* __restrict__ cnt, float* __restrict__ dis, int n) {
    int i = blockIdx.x * blockDim.x + threadIdx.x;
    if (i < n) dis[i] = rsqrtf((float)cnt[i] + 1.0f);
}

// exclusive scan of cnt -> rowptr, 1024 elems per block (256 thr x 4)
__global__ void k_scan1(const int* __restrict__ cnt, int* __restrict__ rowptr,
                        int* __restrict__ part, int n) {
    __shared__ int sums[256];
    int b = blockIdx.x, t = threadIdx.x;
    int base = b * 1024 + t * 4;
    int v0 = (base + 0 < n) ? cnt[base + 0] : 0;
    int v1 = (base + 1 < n) ? cnt[base + 1] : 0;
    int v2 = (base + 2 < n) ? cnt[base + 2] : 0;
    int v3 = (base + 3 < n) ? cnt[base + 3] : 0;
    int tsum = v0 + v1 + v2 + v3;
    sums[t] = tsum;
    __syncthreads();
    for (int off = 1; off < 256; off <<= 1) {
        int y = (t >= off) ? sums[t - off] : 0;
        __syncthreads();
        sums[t] += y;
        __syncthreads();
    }
    int excl = sums[t] - tsum;
    if (base + 0 < n) rowptr[base + 0] = excl;
    if (base + 1 < n) rowptr[base + 1] = excl + v0;
    if (base + 2 < n) rowptr[base + 2] = excl + v0 + v1;
    if (base + 3 < n) rowptr[base + 3] = excl + v0 + v1 + v2;
    if (t == 255) part[b] = sums[255];
}

__global__ void k_scan2(int* __restrict__ part, int nb) {
    __shared__ int sums[256];
    int t = threadIdx.x;
    int v = (t < nb) ? part[t] : 0;
    sums[t] = v;
    __syncthreads();
    for (int off = 1; off < 256; off <<= 1) {
        int y = (t >= off) ? sums[t - off] : 0;
        __syncthreads();
        sums[t] += y;
        __syncthreads();
    }
    if (t < nb) part[t] = sums[t] - v;   // exclusive
}

__global__ void k_scan3(int* __restrict__ rowptr, const int* __restrict__ part,
                        int n, int total) {
    int i = blockIdx.x * blockDim.x + threadIdx.x;
    if (i < n) rowptr[i] += part[i >> 10];
    if (i == 0) rowptr[n] = total;
}

__global__ void k_fill(const int* __restrict__ src, const int* __restrict__ dst,
                       const int* __restrict__ rowptr, int* __restrict__ cursor,
                       int* __restrict__ e_src, int e) {
    int i = blockIdx.x * blockDim.x + threadIdx.x;
    if (i >= e) return;
    int t = dst[i];
    int pos = atomicAdd(&cursor[t], 1);
    e_src[rowptr[t] + pos] = src[i];
}
// ---------------------------------------------------------------------------

// C[M,N] = op(A[M,K]) @ B[K,N] (+ bias). op = relu if RELU_A.
// 64x64 tile, BK=16, 256 threads, 4x4 micro-tile. K%16==0, N%64==0.
template<bool RELU_A>
__global__ void k_sgemm(const float* __restrict__ A, const float* __restrict__ B,
                        const float* __restrict__ bias, float* __restrict__ C,
                        int M, int K, int N) {
    __shared__ float As[16][65];
    __shared__ float Bs[16][65];
    const int bm = blockIdx.x * 64;
    const int bn = blockIdx.y * 64;
    const int tid = threadIdx.x;
    const int tx = tid & 15;
    const int ty = tid >> 4;

    float acc[4][4] = {};

    for (int k0 = 0; k0 < K; k0 += 16) {
        #pragma unroll
        for (int i = tid; i < 64 * 16; i += 256) {
            int r = i >> 4, c = i & 15;
            float v = 0.f;
            if (bm + r < M) {
                v = A[(size_t)(bm + r) * K + (k0 + c)];
                if (RELU_A) v = fmaxf(v, 0.f);
            }
            As[c][r] = v;
        }
        #pragma unroll
        for (int i = tid; i < 16 * 64; i += 256) {
            int kk = i >> 6, c = i & 63;
            Bs[kk][c] = B[(size_t)(k0 + kk) * N + (bn + c)];
        }
        __syncthreads();
        #pragma unroll
        for (int kk = 0; kk < 16; ++kk) {
            float a[4], b[4];
            #pragma unroll
            for (int i = 0; i < 4; ++i) a[i] = As[kk][ty * 4 + i];
            #pragma unroll
            for (int j = 0; j < 4; ++j) b[j] = Bs[kk][tx * 4 + j];
            #pragma unroll
            for (int i = 0; i < 4; ++i)
                #pragma unroll
                for (int j = 0; j < 4; ++j) acc[i][j] += a[i] * b[j];
        }
        __syncthreads();
    }

    #pragma unroll
    for (int i = 0; i < 4; ++i) {
        int r = bm + ty * 4 + i;
        if (r < M) {
            #pragma unroll
            for (int j = 0; j < 4; ++j) {
                int c = bn + tx * 4 + j;
                float v = acc[i][j];
                if (bias) v += bias[c];
                C[(size_t)r * N + c] = v;
            }
        }
    }
}

// One wave per dst node: out[j] = dis[j]^2 * f[j] + sum_{s in N(j)} dis[s]*dis[j]*f[s] (+bias)
template<int D>
__global__ void k_gather(const float* __restrict__ f, const float* __restrict__ dis,
                         const int* __restrict__ rowptr, const int* __restrict__ e_src,
                         const float* __restrict__ bias, float* __restrict__ outb, int n) {
    int wid = (int)(((long long)blockIdx.x * blockDim.x + threadIdx.x) >> 6);
    int lane = threadIdx.x & 63;
    if (wid >= n) return;
    float dj = dis[wid];
    int r0 = rowptr[wid], r1 = rowptr[wid + 1];

    if constexpr (D == 256) {
        float4 a = reinterpret_cast<const float4*>(f + (size_t)wid * D)[lane];
        float wself = dj * dj;
        float ax = a.x * wself, ay = a.y * wself, az = a.z * wself, aw = a.w * wself;
        int e = r0;
        for (; e + 1 < r1; e += 2) {
            int s0 = __builtin_amdgcn_readfirstlane(e_src[e]);
            int s1 = __builtin_amdgcn_readfirstlane(e_src[e + 1]);
            float we0 = dis[s0] * dj, we1 = dis[s1] * dj;
            float4 u0 = reinterpret_cast<const float4*>(f + (size_t)s0 * D)[lane];
            float4 u1 = reinterpret_cast<const float4*>(f + (size_t)s1 * D)[lane];
            ax += u0.x * we0 + u1.x * we1;
            ay += u0.y * we0 + u1.y * we1;
            az += u0.z * we0 + u1.z * we1;
            aw += u0.w * we0 + u1.w * we1;
        }
        if (e < r1) {
            int s0 = __builtin_amdgcn_readfirstlane(e_src[e]);
            float we0 = dis[s0] * dj;
            float4 u0 = reinterpret_cast<const float4*>(f + (size_t)s0 * D)[lane];
            ax += u0.x * we0; ay += u0.y * we0; az += u0.z * we0; aw += u0.w * we0;
        }
        if (bias) {
            float4 bb = reinterpret_cast<const float4*>(bias)[lane];
            ax += bb.x; ay += bb.y; az += bb.z; aw += bb.w;
        }
        reinterpret_cast<float4*>(outb + (size_t)wid * D)[lane] = make_float4(ax, ay, az, aw);
    } else {  // D == 128: float2 per lane
        float2 a = reinterpret_cast<const float2*>(f + (size_t)wid * D)[lane];
        float wself = dj * dj;
        float ax = a.x * wself, ay = a.y * wself;
        int e = r0;
        for (; e + 1 < r1; e += 2) {
            int s0 = __builtin_amdgcn_readfirstlane(e_src[e]);
            int s1 = __builtin_amdgcn_readfirstlane(e_src[e + 1]);
            float we0 = dis[s0] * dj, we1 = dis[s1] * dj;
            float2 u0 = reinterpret_cast<const float2*>(f + (size_t)s0 * D)[lane];
            float2 u1 = reinterpret_cast<const float2*>(f + (size_t)s1 * D)[lane];
            ax += u0.x * we0 + u1.x * we1;
            ay += u0.y * we0 + u1.y * we1;
        }
        if (e < r1) {
            int s0 = __builtin_amdgcn_readfirstlane(e_src[e]);
            float we0 = dis[s0] * dj;
            float2 u0 = reinterpret_cast<const float2*>(f + (size_t)s0 * D)[lane];
            ax += u0.x * we0; ay += u0.y * we0;
        }
        if (bias) {
            float2 bb = reinterpret_cast<const float2*>(bias)[lane];
            ax += bb.x; ay += bb.y;
        }
        reinterpret_cast<float2*>(outb + (size_t)wid * D)[lane] = make_float2(ax, ay);
    }
}

extern "C" void kernel_launch(void* const* d_in, const int* in_sizes, int n_in,
                              void* d_out, int out_size, void* d_ws, size_t ws_size,
                              hipStream_t stream) {
    const float* x1  = (const float*)d_in[0];
    const float* x2  = (const float*)d_in[1];
    const float* x3  = (const float*)d_in[2];
    const float* Wp1 = (const float*)d_in[3];
    const float* bp1 = (const float*)d_in[4];
    const float* Wp2 = (const float*)d_in[5];
    const float* bp2 = (const float*)d_in[6];
    const float* Wp3 = (const float*)d_in[7];
    const float* bp3 = (const float*)d_in[8];
    const float* W1  = (const float*)d_in[9];   // (256,256)
    const float* b1  = (const float*)d_in[10];
    const float* W2  = (const float*)d_in[11];  // (256,128)
    const float* b2  = (const float*)d_in[12];
    const int*   ei  = (const int*)d_in[13];    // int32
    const int* src = ei;
    const int* dst = ei + EE;
    float* out = (float*)d_out;

    // workspace (~210 MB)
    char* ws = (char*)d_ws;
    size_t off = 0;
    auto alloc = [&](size_t bytes) {
        char* p = ws + off;
        off += (bytes + 511) & ~(size_t)511;
        return p;
    };
    float* dis    = (float*)alloc((size_t)NT * 4);
    int*   cnt    = (int*)alloc((size_t)NT * 4);
    int*   cursor = (int*)alloc((size_t)NT * 4);
    int*   rowptr = (int*)alloc((size_t)(NT + 1) * 4);
    int*   part   = (int*)alloc(256 * 4);
    int*   e_src  = (int*)alloc((size_t)EE * 4);
    float* slotA  = (float*)alloc((size_t)NT * DIN * 4);   // x, then h
    float* slotB  = (float*)alloc((size_t)NT * DIN * 4);   // aggX, then hW2

    float* x    = slotA;
    float* aggX = slotB;
    float* h    = slotA;
    float* hW2  = slotB;

    const int nb = cdiv(NT, 1024);   // 98 scan blocks

    // 0) CSR build + dis
    k_zero_i32<<<cdiv(NT, 256), 256, 0, stream>>>(cnt, NT);
    k_zero_i32<<<cdiv(NT, 256), 256, 0, stream>>>(cursor, NT);
    k_hist<<<cdiv(EE, 256), 256, 0, stream>>>(dst, cnt, EE);
    k_dis<<<cdiv(NT, 256), 256, 0, stream>>>(cnt, dis, NT);
    k_scan1<<<nb, 256, 0, stream>>>(cnt, rowptr, part, NT);
    k_scan2<<<1, 256, 0, stream>>>(part, nb);
    k_scan3<<<cdiv(NT, 256), 256, 0, stream>>>(rowptr, part, NT, EE);
    k_fill<<<cdiv(EE, 256), 256, 0, stream>>>(src, dst, rowptr, cursor, e_src, EE);

    // 1) per-type projections into x
    {
        dim3 g1(cdiv(NN1, 64), DIN / 64);
        k_sgemm<false><<<g1, 256, 0, stream>>>(x1, Wp1, bp1, x, NN1, 128, DIN);
        dim3 g2(cdiv(NN2, 64), DIN / 64);
        k_sgemm<false><<<g2, 256, 0, stream>>>(x2, Wp2, bp2, x + (size_t)NN1 * DIN, NN2, 256, DIN);
        dim3 g3(cdiv(NN3, 64), DIN / 64);
        k_sgemm<false><<<g3, 256, 0, stream>>>(x3, Wp3, bp3, x + (size_t)(NN1 + NN2) * DIN, NN3, 64, DIN);
    }

    // 2) aggX = Â x   (gather, no atomics; Â(XW1) = (ÂX)W1 by linearity)
    k_gather<DIN><<<cdiv(NT * 64, 256), 256, 0, stream>>>(x, dis, rowptr, e_src, nullptr, aggX, NT);

    // 3) h = aggX @ W1 + b1
    {
        dim3 g(cdiv(NT, 64), DHID / 64);
        k_sgemm<false><<<g, 256, 0, stream>>>(aggX, W1, b1, h, NT, DIN, DHID);
    }

    // 4) hW2 = relu(h) @ W2
    {
        dim3 g(cdiv(NT, 64), DOUT / 64);
        k_sgemm<true><<<g, 256, 0, stream>>>(h, W2, nullptr, hW2, NT, DHID, DOUT);
    }

    // 5) out = Â hW2 + b2   (gather + bias fused)
    k_gather<DOUT><<<cdiv(NT * 64, 256), 256, 0, stream>>>(hW2, dis, rowptr, e_src, b2, out, NT);
}

// Round 6
// 373.604 us; speedup vs baseline: 11.0942x; 2.6206x over previous
//
#include <hip/hip_runtime.h>
#include <cstddef>

#define NT 100000
#define NN1 40000
#define NN2 30000
#define NN3 30000
#define EE 800000
#define DIN 256
#define DHID 256
#define DOUT 128

typedef _Float16 f16;
typedef f16 f16x8 __attribute__((ext_vector_type(8)));
typedef f16 f16x4 __attribute__((ext_vector_type(4)));
typedef f16 f16x2 __attribute__((ext_vector_type(2)));
typedef float f32x4 __attribute__((ext_vector_type(4)));

static inline int cdiv(int a, int b) { return (a + b - 1) / b; }

// ---------------- CSR build (dst-sorted adjacency) --------------------------
__global__ void k_zero_i32(int* __restrict__ p, int n) {
    int i = blockIdx.x * blockDim.x + threadIdx.x;
    if (i < n) p[i] = 0;
}

__global__ void k_hist(const int* __restrict__ dst, int* __restrict__ cnt, int e) {
    int i = blockIdx.x * blockDim.x + threadIdx.x;
    if (i < e) atomicAdd(&cnt[dst[i]], 1);
}

__global__ void k_dis(const int* __restrict__ cnt, float* __restrict__ dis, int n) {
    int i = blockIdx.x * blockDim.x + threadIdx.x;
    if (i < n) dis[i] = rsqrtf((float)cnt[i] + 1.0f);
}

__global__ void k_scan1(const int* __restrict__ cnt, int* __restrict__ rowptr,
                        int* __restrict__ part, int n) {
    __shared__ int sums[256];
    int b = blockIdx.x, t = threadIdx.x;
    int base = b * 1024 + t * 4;
    int v0 = (base + 0 < n) ? cnt[base + 0] : 0;
    int v1 = (base + 1 < n) ? cnt[base + 1] : 0;
    int v2 = (base + 2 < n) ? cnt[base + 2] : 0;
    int v3 = (base + 3 < n) ? cnt[base + 3] : 0;
    int tsum = v0 + v1 + v2 + v3;
    sums[t] = tsum;
    __syncthreads();
    for (int off = 1; off < 256; off <<= 1) {
        int y = (t >= off) ? sums[t - off] : 0;
        __syncthreads();
        sums[t] += y;
        __syncthreads();
    }
    int excl = sums[t] - tsum;
    if (base + 0 < n) rowptr[base + 0] = excl;
    if (base + 1 < n) rowptr[base + 1] = excl + v0;
    if (base + 2 < n) rowptr[base + 2] = excl + v0 + v1;
    if (base + 3 < n) rowptr[base + 3] = excl + v0 + v1 + v2;
    if (t == 255) part[b] = sums[255];
}

__global__ void k_scan2(int* __restrict__ part, int nb) {
    __shared__ int sums[256];
    int t = threadIdx.x;
    int v = (t < nb) ? part[t] : 0;
    sums[t] = v;
    __syncthreads();
    for (int off = 1; off < 256; off <<= 1) {
        int y = (t >= off) ? sums[t - off] : 0;
        __syncthreads();
        sums[t] += y;
        __syncthreads();
    }
    if (t < nb) part[t] = sums[t] - v;
}

__global__ void k_scan3(int* __restrict__ rowptr, const int* __restrict__ part,
                        int n, int total) {
    int i = blockIdx.x * blockDim.x + threadIdx.x;
    if (i < n) rowptr[i] += part[i >> 10];
    if (i == 0) rowptr[n] = total;
}

__global__ void k_fill(const int* __restrict__ src, const int* __restrict__ dst,
                       const int* __restrict__ rowptr, int* __restrict__ cursor,
                       int* __restrict__ e_src, int e) {
    int i = blockIdx.x * blockDim.x + threadIdx.x;
    if (i >= e) return;
    int t = dst[i];
    int pos = atomicAdd(&cursor[t], 1);
    e_src[rowptr[t] + pos] = src[i];
}

// ---------------- dtype prep ------------------------------------------------
__global__ void k_cvt_f16(const float* __restrict__ in, f16* __restrict__ o, int n4) {
    int i = blockIdx.x * blockDim.x + threadIdx.x;
    if (i >= n4) return;
    float4 v = reinterpret_cast<const float4*>(in)[i];
    f16x4 r = {(f16)v.x, (f16)v.y, (f16)v.z, (f16)v.w};
    reinterpret_cast<f16x4*>(o)[i] = r;
}

// WT[n*K + k] = (f16) W[k*N + n]
__global__ void k_transpose_w(const float* __restrict__ W, f16* __restrict__ WT,
                              int K, int N) {
    int i = blockIdx.x * blockDim.x + threadIdx.x;
    if (i >= K * N) return;
    int k = i / N, n = i - k * N;
    WT[n * K + k] = (f16)W[i];
}

// ---------------- f16 MFMA GEMM --------------------------------------------
// C[M,N](f16) = A[M,K](f16) @ BT[N,K](f16)^T (+bias, +relu).
// 128x128 tile, BK=32, 256 thr = 4 waves (2x2), 4x4 16x16x32 frags/wave.
// LDS chunk-XOR swizzle (chunk ^= row&3) on write+read: 2-way banks (free).
// Layouts (verified, guide §3/m89/m91): A-frag A[l&15][(l>>4)*8+j],
// B-frag B[(l>>4)*8+j][l&15] (from BT rows), D row=(l>>4)*4+r, col=l&15.
template<bool RELU_OUT, bool HAS_BIAS>
__global__ __launch_bounds__(256)
void k_hgemm(const f16* __restrict__ A, const f16* __restrict__ BT,
             const float* __restrict__ bias, f16* __restrict__ C,
             int M, int K, int N) {
    __shared__ f16 As[128 * 32];
    __shared__ f16 Bs[128 * 32];
    const int tid = threadIdx.x;
    const int lane = tid & 63;
    const int wid = tid >> 6;
    const int wm = wid & 1, wn = wid >> 1;
    const int bm = blockIdx.x * 128;
    const int bn = blockIdx.y * 128;
    const int r15 = lane & 15, g = lane >> 4;

    f32x4 acc[4][4] = {};

    for (int k0 = 0; k0 < K; k0 += 32) {
        #pragma unroll
        for (int q = 0; q < 2; ++q) {
            int c2 = tid * 2 + q;             // 0..511 -> (row 0..127, chunk 0..3)
            int row = c2 >> 2, ch = c2 & 3;
            int grow = bm + row; if (grow >= M) grow = M - 1;
            f16x8 v = *reinterpret_cast<const f16x8*>(A + (size_t)grow * K + k0 + ch * 8);
            *reinterpret_cast<f16x8*>(As + row * 32 + ((ch ^ (row & 3)) * 8)) = v;
        }
        #pragma unroll
        for (int q = 0; q < 2; ++q) {
            int c2 = tid * 2 + q;
            int row = c2 >> 2, ch = c2 & 3;   // row = n-index (BN=128 exact)
            f16x8 v = *reinterpret_cast<const f16x8*>(BT + (size_t)(bn + row) * K + k0 + ch * 8);
            *reinterpret_cast<f16x8*>(Bs + row * 32 + ((ch ^ (row & 3)) * 8)) = v;
        }
        __syncthreads();

        f16x8 af[4], bf[4];
        #pragma unroll
        for (int mf = 0; mf < 4; ++mf) {
            int row = wm * 64 + mf * 16 + r15;
            af[mf] = *reinterpret_cast<const f16x8*>(As + row * 32 + ((g ^ (row & 3)) * 8));
        }
        #pragma unroll
        for (int nf = 0; nf < 4; ++nf) {
            int row = wn * 64 + nf * 16 + r15;
            bf[nf] = *reinterpret_cast<const f16x8*>(Bs + row * 32 + ((g ^ (row & 3)) * 8));
        }
        #pragma unroll
        for (int mf = 0; mf < 4; ++mf)
            #pragma unroll
            for (int nf = 0; nf < 4; ++nf)
                acc[mf][nf] = __builtin_amdgcn_mfma_f32_16x16x32_f16(af[mf], bf[nf], acc[mf][nf], 0, 0, 0);
        __syncthreads();
    }

    #pragma unroll
    for (int mf = 0; mf < 4; ++mf) {
        #pragma unroll
        for (int nf = 0; nf < 4; ++nf) {
            int col = bn + wn * 64 + nf * 16 + r15;
            float bv = HAS_BIAS ? bias[col] : 0.f;
            #pragma unroll
            for (int r = 0; r < 4; ++r) {
                int rowg = bm + wm * 64 + mf * 16 + g * 4 + r;
                if (rowg < M) {
                    float v = acc[mf][nf][r] + bv;
                    if (RELU_OUT) v = fmaxf(v, 0.f);
                    C[(size_t)rowg * N + col] = (f16)v;
                }
            }
        }
    }
}

// ---------------- gathers (CSR, no atomics) ---------------------------------
// D=256, f16 in -> f16 out, no bias. One wave per dst node.
__global__ void k_gather256(const f16* __restrict__ f, const float* __restrict__ dis,
                            const int* __restrict__ rowptr, const int* __restrict__ e_src,
                            f16* __restrict__ outb, int n) {
    int wid = (int)(((long long)blockIdx.x * blockDim.x + threadIdx.x) >> 6);
    int lane = threadIdx.x & 63;
    if (wid >= n) return;
    float dj = dis[wid];
    int r0 = rowptr[wid], r1 = rowptr[wid + 1];
    f16x4 a = reinterpret_cast<const f16x4*>(f + (size_t)wid * 256)[lane];
    float ws = dj * dj;
    float ax = (float)a[0] * ws, ay = (float)a[1] * ws, az = (float)a[2] * ws, aw = (float)a[3] * ws;
    int e = r0;
    for (; e + 1 < r1; e += 2) {
        int s0 = __builtin_amdgcn_readfirstlane(e_src[e]);
        int s1 = __builtin_amdgcn_readfirstlane(e_src[e + 1]);
        float w0 = dis[s0] * dj, w1 = dis[s1] * dj;
        f16x4 u0 = reinterpret_cast<const f16x4*>(f + (size_t)s0 * 256)[lane];
        f16x4 u1 = reinterpret_cast<const f16x4*>(f + (size_t)s1 * 256)[lane];
        ax += (float)u0[0] * w0 + (float)u1[0] * w1;
        ay += (float)u0[1] * w0 + (float)u1[1] * w1;
        az += (float)u0[2] * w0 + (float)u1[2] * w1;
        aw += (float)u0[3] * w0 + (float)u1[3] * w1;
    }
    if (e < r1) {
        int s0 = __builtin_amdgcn_readfirstlane(e_src[e]);
        float w0 = dis[s0] * dj;
        f16x4 u0 = reinterpret_cast<const f16x4*>(f + (size_t)s0 * 256)[lane];
        ax += (float)u0[0] * w0; ay += (float)u0[1] * w0;
        az += (float)u0[2] * w0; aw += (float)u0[3] * w0;
    }
    f16x4 r = {(f16)ax, (f16)ay, (f16)az, (f16)aw};
    reinterpret_cast<f16x4*>(outb + (size_t)wid * 256)[lane] = r;
}

// D=128, f16 in -> f32 out (+bias). One wave per dst node.
__global__ void k_gather128(const f16* __restrict__ f, const float* __restrict__ dis,
                            const int* __restrict__ rowptr, const int* __restrict__ e_src,
                            const float* __restrict__ bias, float* __restrict__ outb, int n) {
    int wid = (int)(((long long)blockIdx.x * blockDim.x + threadIdx.x) >> 6);
    int lane = threadIdx.x & 63;
    if (wid >= n) return;
    float dj = dis[wid];
    int r0 = rowptr[wid], r1 = rowptr[wid + 1];
    f16x2 a = reinterpret_cast<const f16x2*>(f + (size_t)wid * 128)[lane];
    float ws = dj * dj;
    float ax = (float)a[0] * ws, ay = (float)a[1] * ws;
    int e = r0;
    for (; e + 1 < r1; e += 2) {
        int s0 = __builtin_amdgcn_readfirstlane(e_src[e]);
        int s1 = __builtin_amdgcn_readfirstlane(e_src[e + 1]);
        float w0 = dis[s0] * dj, w1 = dis[s1] * dj;
        f16x2 u0 = reinterpret_cast<const f16x2*>(f + (size_t)s0 * 128)[lane];
        f16x2 u1 = reinterpret_cast<const f16x2*>(f + (size_t)s1 * 128)[lane];
        ax += (float)u0[0] * w0 + (float)u1[0] * w1;
        ay += (float)u0[1] * w0 + (float)u1[1] * w1;
    }
    if (e < r1) {
        int s0 = __builtin_amdgcn_readfirstlane(e_src[e]);
        float w0 = dis[s0] * dj;
        f16x2 u0 = reinterpret_cast<const f16x2*>(f + (size_t)s0 * 128)[lane];
        ax += (float)u0[0] * w0; ay += (float)u0[1] * w0;
    }
    float2 bb = reinterpret_cast<const float2*>(bias)[lane];
    reinterpret_cast<float2*>(outb + (size_t)wid * 128)[lane] = make_float2(ax + bb.x, ay + bb.y);
}

extern "C" void kernel_launch(void* const* d_in, const int* in_sizes, int n_in,
                              void* d_out, int out_size, void* d_ws, size_t ws_size,
                              hipStream_t stream) {
    const float* x1  = (const float*)d_in[0];
    const float* x2  = (const float*)d_in[1];
    const float* x3  = (const float*)d_in[2];
    const float* Wp1 = (const float*)d_in[3];
    const float* bp1 = (const float*)d_in[4];
    const float* Wp2 = (const float*)d_in[5];
    const float* bp2 = (const float*)d_in[6];
    const float* Wp3 = (const float*)d_in[7];
    const float* bp3 = (const float*)d_in[8];
    const float* W1  = (const float*)d_in[9];
    const float* b1  = (const float*)d_in[10];
    const float* W2  = (const float*)d_in[11];
    const float* b2  = (const float*)d_in[12];
    const int*   ei  = (const int*)d_in[13];
    const int* src = ei;
    const int* dst = ei + EE;
    float* out = (float*)d_out;

    // workspace (~140 MB)
    char* ws = (char*)d_ws;
    size_t off = 0;
    auto alloc = [&](size_t bytes) {
        char* p = ws + off;
        off += (bytes + 511) & ~(size_t)511;
        return p;
    };
    float* dis    = (float*)alloc((size_t)NT * 4);
    int*   cnt    = (int*)alloc((size_t)NT * 4);
    int*   cursor = (int*)alloc((size_t)NT * 4);
    int*   rowptr = (int*)alloc((size_t)(NT + 1) * 4);
    int*   part   = (int*)alloc(256 * 4);
    int*   e_src  = (int*)alloc((size_t)EE * 4);
    f16*   slotX  = (f16*)alloc((size_t)NT * 256 * 2);   // x16, then h16
    f16*   slotY  = (f16*)alloc((size_t)NT * 256 * 2);   // agg16, then hw216
    f16*   x1c    = (f16*)alloc((size_t)NN1 * 128 * 2);
    f16*   x2c    = (f16*)alloc((size_t)NN2 * 256 * 2);
    f16*   x3c    = (f16*)alloc((size_t)NN3 * 64 * 2);
    f16*   Wp1T   = (f16*)alloc((size_t)256 * 128 * 2);
    f16*   Wp2T   = (f16*)alloc((size_t)256 * 256 * 2);
    f16*   Wp3T   = (f16*)alloc((size_t)256 * 64 * 2);
    f16*   W1T    = (f16*)alloc((size_t)256 * 256 * 2);
    f16*   W2T    = (f16*)alloc((size_t)128 * 256 * 2);

    f16* x16   = slotX;
    f16* agg16 = slotY;
    f16* h16   = slotX;
    f16* hw216 = slotY;

    const int nb = cdiv(NT, 1024);

    // 0) CSR build + dis
    k_zero_i32<<<cdiv(NT, 256), 256, 0, stream>>>(cnt, NT);
    k_zero_i32<<<cdiv(NT, 256), 256, 0, stream>>>(cursor, NT);
    k_hist<<<cdiv(EE, 256), 256, 0, stream>>>(dst, cnt, EE);
    k_dis<<<cdiv(NT, 256), 256, 0, stream>>>(cnt, dis, NT);
    k_scan1<<<nb, 256, 0, stream>>>(cnt, rowptr, part, NT);
    k_scan2<<<1, 256, 0, stream>>>(part, nb);
    k_scan3<<<cdiv(NT, 256), 256, 0, stream>>>(rowptr, part, NT, EE);
    k_fill<<<cdiv(EE, 256), 256, 0, stream>>>(src, dst, rowptr, cursor, e_src, EE);

    // 1) dtype prep
    k_cvt_f16<<<cdiv(NN1 * 128 / 4, 256), 256, 0, stream>>>(x1, x1c, NN1 * 128 / 4);
    k_cvt_f16<<<cdiv(NN2 * 256 / 4, 256), 256, 0, stream>>>(x2, x2c, NN2 * 256 / 4);
    k_cvt_f16<<<cdiv(NN3 * 64 / 4, 256), 256, 0, stream>>>(x3, x3c, NN3 * 64 / 4);
    k_transpose_w<<<cdiv(128 * 256, 256), 256, 0, stream>>>(Wp1, Wp1T, 128, 256);
    k_transpose_w<<<cdiv(256 * 256, 256), 256, 0, stream>>>(Wp2, Wp2T, 256, 256);
    k_transpose_w<<<cdiv(64 * 256, 256), 256, 0, stream>>>(Wp3, Wp3T, 64, 256);
    k_transpose_w<<<cdiv(256 * 256, 256), 256, 0, stream>>>(W1, W1T, 256, 256);
    k_transpose_w<<<cdiv(256 * 128, 256), 256, 0, stream>>>(W2, W2T, 256, 128);

    // 2) projections -> x16
    {
        dim3 g1(cdiv(NN1, 128), 2);
        k_hgemm<false, true><<<g1, 256, 0, stream>>>(x1c, Wp1T, bp1, x16, NN1, 128, 256);
        dim3 g2(cdiv(NN2, 128), 2);
        k_hgemm<false, true><<<g2, 256, 0, stream>>>(x2c, Wp2T, bp2, x16 + (size_t)NN1 * 256, NN2, 256, 256);
        dim3 g3(cdiv(NN3, 128), 2);
        k_hgemm<false, true><<<g3, 256, 0, stream>>>(x3c, Wp3T, bp3, x16 + (size_t)(NN1 + NN2) * 256, NN3, 64, 256);
    }

    // 3) agg16 = Â x16   (gather; Â(XW1) = (ÂX)W1 by linearity)
    k_gather256<<<cdiv(NT * 64, 256), 256, 0, stream>>>(x16, dis, rowptr, e_src, agg16, NT);

    // 4) h16 = relu(agg16 @ W1 + b1)
    {
        dim3 g(cdiv(NT, 128), 2);
        k_hgemm<true, true><<<g, 256, 0, stream>>>(agg16, W1T, b1, h16, NT, 256, 256);
    }

    // 5) hw216 = h16 @ W2
    {
        dim3 g(cdiv(NT, 128), 1);
        k_hgemm<false, false><<<g, 256, 0, stream>>>(h16, W2T, nullptr, hw216, NT, 256, 128);
    }

    // 6) out = Â hw216 + b2  (f32 output)
    k_gather128<<<cdiv(NT * 64, 256), 256, 0, stream>>>(hw216, dis, rowptr, e_src, b2, out, NT);
}

// Round 7
// 331.225 us; speedup vs baseline: 12.5137x; 1.1279x over previous
//
#include <hip/hip_runtime.h>
#include <cstddef>

#define NT 100000
#define NN1 40000
#define NN2 30000
#define NN3 30000
#define EE 800000
#define DIN 256
#define DHID 256
#define DOUT 128

typedef _Float16 f16;
typedef f16 f16x8 __attribute__((ext_vector_type(8)));
typedef f16 f16x4 __attribute__((ext_vector_type(4)));
typedef f16 f16x2 __attribute__((ext_vector_type(2)));
typedef float f32x4 __attribute__((ext_vector_type(4)));

static inline int cdiv(int a, int b) { return (a + b - 1) / b; }

// async global->LDS, 16B per lane; LDS dest = wave-uniform base + lane*16
__device__ __forceinline__ void gload_lds16(const f16* g, f16* l) {
    __builtin_amdgcn_global_load_lds(
        (const __attribute__((address_space(1))) void*)g,
        (__attribute__((address_space(3))) void*)l, 16, 0, 0);
}

// ---------------- CSR build (dst-sorted adjacency) --------------------------
__global__ void k_hist(const int* __restrict__ dst, int* __restrict__ cnt, int e) {
    int i = blockIdx.x * blockDim.x + threadIdx.x;
    if (i < e) atomicAdd(&cnt[dst[i]], 1);
}

// exclusive scan (phase 1) + dis = rsqrt(cnt+1) fused
__global__ void k_scan1(const int* __restrict__ cnt, int* __restrict__ rowptr,
                        int* __restrict__ part, float* __restrict__ dis, int n) {
    __shared__ int sums[256];
    int b = blockIdx.x, t = threadIdx.x;
    int base = b * 1024 + t * 4;
    int v0 = (base + 0 < n) ? cnt[base + 0] : 0;
    int v1 = (base + 1 < n) ? cnt[base + 1] : 0;
    int v2 = (base + 2 < n) ? cnt[base + 2] : 0;
    int v3 = (base + 3 < n) ? cnt[base + 3] : 0;
    if (base + 0 < n) dis[base + 0] = rsqrtf((float)v0 + 1.0f);
    if (base + 1 < n) dis[base + 1] = rsqrtf((float)v1 + 1.0f);
    if (base + 2 < n) dis[base + 2] = rsqrtf((float)v2 + 1.0f);
    if (base + 3 < n) dis[base + 3] = rsqrtf((float)v3 + 1.0f);
    int tsum = v0 + v1 + v2 + v3;
    sums[t] = tsum;
    __syncthreads();
    for (int off = 1; off < 256; off <<= 1) {
        int y = (t >= off) ? sums[t - off] : 0;
        __syncthreads();
        sums[t] += y;
        __syncthreads();
    }
    int excl = sums[t] - tsum;
    if (base + 0 < n) rowptr[base + 0] = excl;
    if (base + 1 < n) rowptr[base + 1] = excl + v0;
    if (base + 2 < n) rowptr[base + 2] = excl + v0 + v1;
    if (base + 3 < n) rowptr[base + 3] = excl + v0 + v1 + v2;
    if (t == 255) part[b] = sums[255];
}

__global__ void k_scan2(int* __restrict__ part, int nb) {
    __shared__ int sums[256];
    int t = threadIdx.x;
    int v = (t < nb) ? part[t] : 0;
    sums[t] = v;
    __syncthreads();
    for (int off = 1; off < 256; off <<= 1) {
        int y = (t >= off) ? sums[t - off] : 0;
        __syncthreads();
        sums[t] += y;
        __syncthreads();
    }
    if (t < nb) part[t] = sums[t] - v;
}

__global__ void k_scan3(int* __restrict__ rowptr, const int* __restrict__ part,
                        int n, int total) {
    int i = blockIdx.x * blockDim.x + threadIdx.x;
    if (i < n) rowptr[i] += part[i >> 10];
    if (i == 0) rowptr[n] = total;
}

__global__ void k_fill(const int* __restrict__ src, const int* __restrict__ dst,
                       const int* __restrict__ rowptr, int* __restrict__ cursor,
                       int* __restrict__ e_src, int e) {
    int i = blockIdx.x * blockDim.x + threadIdx.x;
    if (i >= e) return;
    int t = dst[i];
    int pos = atomicAdd(&cursor[t], 1);
    e_src[rowptr[t] + pos] = src[i];
}

// ---------------- dtype prep (merged) ---------------------------------------
// xc = [x1c | x2c | x3c] contiguous f16; segment sizes in float4 units
__global__ void k_cvt_all(const float* __restrict__ a, int na4,
                          const float* __restrict__ b, int nb4,
                          const float* __restrict__ c, int nc4,
                          f16* __restrict__ o) {
    int i = blockIdx.x * blockDim.x + threadIdx.x;
    const float* s; int j;
    if (i < na4) { s = a; j = i; }
    else if (i < na4 + nb4) { s = b; j = i - na4; }
    else if (i < na4 + nb4 + nc4) { s = c; j = i - na4 - nb4; }
    else return;
    float4 v = reinterpret_cast<const float4*>(s)[j];
    f16x4 r = {(f16)v.x, (f16)v.y, (f16)v.z, (f16)v.w};
    reinterpret_cast<f16x4*>(o)[i] = r;
}

struct TArgs {
    const float *W0, *W1, *W2, *W3, *W4;
    f16 *T0, *T1, *T2, *T3, *T4;
};
// all 5 weight transposes (f32 [K][N] -> f16 [N][K]) in one kernel
__global__ void k_transpose_all(TArgs t) {
    int i = blockIdx.x * blockDim.x + threadIdx.x;
    const float* W; f16* T; int K, N, j;
    if      (i <  32768) { W = t.W0; T = t.T0; K = 128; N = 256; j = i; }
    else if (i <  98304) { W = t.W1; T = t.T1; K = 256; N = 256; j = i - 32768; }
    else if (i < 114688) { W = t.W2; T = t.T2; K =  64; N = 256; j = i - 98304; }
    else if (i < 180224) { W = t.W3; T = t.T3; K = 256; N = 256; j = i - 114688; }
    else if (i < 212992) { W = t.W4; T = t.T4; K = 256; N = 128; j = i - 180224; }
    else return;
    int k = j / N, n = j - k * N;
    T[n * K + k] = (f16)W[j];
}

// ---------------- f16 MFMA GEMM, global_load_lds + double-buffer ------------
// C[M,N](f16) = A[M,K](f16) @ BT[N,K]^T (+bias,+relu). 128x128 tile, BK=32,
// 256 thr = 4 waves (2x2). LDS slot swizzle: slot = ch ^ ((row>>1)&3) -> 2-way
// banks on ds_read_b128 (free, m136). gload_lds dest linear; swizzle applied
// on the per-lane GLOBAL source address (rule #21).
template<bool RELU_OUT, bool HAS_BIAS>
__global__ __launch_bounds__(256)
void k_hgemm(const f16* __restrict__ A, const f16* __restrict__ BT,
             const float* __restrict__ bias, f16* __restrict__ C,
             int M, int K, int N) {
    __shared__ f16 As[2][4096];   // [buf][128 rows x 32]
    __shared__ f16 Bs[2][4096];
    const int tid = threadIdx.x;
    const int lane = tid & 63;
    const int wid = tid >> 6;
    const int wm = wid & 1, wn = wid >> 1;
    const int bm = blockIdx.x * 128;
    const int bn = blockIdx.y * 128;
    const int r15 = lane & 15, g = lane >> 4;
    // staging: wave wid covers chunks {wid, wid+4}; per-lane slot geometry
    const int sr  = lane >> 2;                      // row within chunk (0..15)
    const int chs = (lane & 3) ^ ((lane >> 3) & 3); // source k-chunk for slot

    auto stage = [&](int buf, int k0) {
        #pragma unroll
        for (int q = 0; q < 2; ++q) {
            int chunk = wid + q * 4;                // 0..7
            int row = chunk * 16 + sr;              // 0..127
            int ga = bm + row; if (ga >= M) ga = M - 1;
            gload_lds16(A  + (size_t)ga * K + k0 + chs * 8, &As[buf][chunk * 512]);
            gload_lds16(BT + (size_t)(bn + row) * K + k0 + chs * 8, &Bs[buf][chunk * 512]);
        }
    };

    f32x4 acc[4][4] = {};
    const int nsteps = K >> 5;
    stage(0, 0);
    __syncthreads();
    int cur = 0;
    for (int step = 0; step < nsteps; ++step) {
        if (step + 1 < nsteps) stage(cur ^ 1, (step + 1) << 5);  // overlap with MFMA
        f16x8 af[4], bf[4];
        const int sl = (g ^ ((r15 >> 1) & 3)) * 8;  // per-lane slot offset (hoisted)
        #pragma unroll
        for (int mf = 0; mf < 4; ++mf) {
            int row = wm * 64 + mf * 16 + r15;
            af[mf] = *reinterpret_cast<const f16x8*>(&As[cur][row * 32 + sl]);
        }
        #pragma unroll
        for (int nf = 0; nf < 4; ++nf) {
            int row = wn * 64 + nf * 16 + r15;
            bf[nf] = *reinterpret_cast<const f16x8*>(&Bs[cur][row * 32 + sl]);
        }
        #pragma unroll
        for (int mf = 0; mf < 4; ++mf)
            #pragma unroll
            for (int nf = 0; nf < 4; ++nf)
                acc[mf][nf] = __builtin_amdgcn_mfma_f32_16x16x32_f16(af[mf], bf[nf], acc[mf][nf], 0, 0, 0);
        __syncthreads();   // drains vmcnt (next buf ready) + lgkmcnt
        cur ^= 1;
    }

    #pragma unroll
    for (int mf = 0; mf < 4; ++mf) {
        #pragma unroll
        for (int nf = 0; nf < 4; ++nf) {
            int col = bn + wn * 64 + nf * 16 + r15;
            float bv = HAS_BIAS ? bias[col] : 0.f;
            #pragma unroll
            for (int r = 0; r < 4; ++r) {
                int rowg = bm + wm * 64 + mf * 16 + g * 4 + r;
                if (rowg < M) {
                    float v = acc[mf][nf][r] + bv;
                    if (RELU_OUT) v = fmaxf(v, 0.f);
                    C[(size_t)rowg * N + col] = (f16)v;
                }
            }
        }
    }
}

// ---------------- gathers (CSR, no atomics, shfl-broadcast + unroll-4) ------
__global__ void k_gather256(const f16* __restrict__ f, const float* __restrict__ dis,
                            const int* __restrict__ rowptr, const int* __restrict__ e_src,
                            f16* __restrict__ outb, int n) {
    int wid = (int)(((long long)blockIdx.x * blockDim.x + threadIdx.x) >> 6);
    int lane = threadIdx.x & 63;
    if (wid >= n) return;
    float dj = dis[wid];
    int r0 = rowptr[wid], r1 = rowptr[wid + 1];
    int deg = r1 - r0;
    int si = 0; float wi = 0.f;
    if (lane < deg) { si = e_src[r0 + lane]; wi = dis[si]; }
    f16x4 a = reinterpret_cast<const f16x4*>(f + (size_t)wid * 256)[lane];
    float ws = dj * dj;
    float ax = (float)a[0] * ws, ay = (float)a[1] * ws, az = (float)a[2] * ws, aw = (float)a[3] * ws;
    int n64 = deg < 64 ? deg : 64;
    int e = 0;
    for (; e + 4 <= n64; e += 4) {
        int s0 = __shfl(si, e + 0), s1 = __shfl(si, e + 1);
        int s2 = __shfl(si, e + 2), s3 = __shfl(si, e + 3);
        float w0 = __shfl(wi, e + 0) * dj, w1 = __shfl(wi, e + 1) * dj;
        float w2 = __shfl(wi, e + 2) * dj, w3 = __shfl(wi, e + 3) * dj;
        f16x4 u0 = reinterpret_cast<const f16x4*>(f + (size_t)s0 * 256)[lane];
        f16x4 u1 = reinterpret_cast<const f16x4*>(f + (size_t)s1 * 256)[lane];
        f16x4 u2 = reinterpret_cast<const f16x4*>(f + (size_t)s2 * 256)[lane];
        f16x4 u3 = reinterpret_cast<const f16x4*>(f + (size_t)s3 * 256)[lane];
        ax += (float)u0[0] * w0 + (float)u1[0] * w1 + (float)u2[0] * w2 + (float)u3[0] * w3;
        ay += (float)u0[1] * w0 + (float)u1[1] * w1 + (float)u2[1] * w2 + (float)u3[1] * w3;
        az += (float)u0[2] * w0 + (float)u1[2] * w1 + (float)u2[2] * w2 + (float)u3[2] * w3;
        aw += (float)u0[3] * w0 + (float)u1[3] * w1 + (float)u2[3] * w2 + (float)u3[3] * w3;
    }
    for (; e < n64; ++e) {
        int s0 = __shfl(si, e); float w0 = __shfl(wi, e) * dj;
        f16x4 u0 = reinterpret_cast<const f16x4*>(f + (size_t)s0 * 256)[lane];
        ax += (float)u0[0] * w0; ay += (float)u0[1] * w0;
        az += (float)u0[2] * w0; aw += (float)u0[3] * w0;
    }
    for (int e2 = r0 + 64; e2 < r1; ++e2) {   // deg>64 tail (not hit in practice)
        int s0 = __builtin_amdgcn_readfirstlane(e_src[e2]);
        float w0 = dis[s0] * dj;
        f16x4 u0 = reinterpret_cast<const f16x4*>(f + (size_t)s0 * 256)[lane];
        ax += (float)u0[0] * w0; ay += (float)u0[1] * w0;
        az += (float)u0[2] * w0; aw += (float)u0[3] * w0;
    }
    f16x4 r = {(f16)ax, (f16)ay, (f16)az, (f16)aw};
    reinterpret_cast<f16x4*>(outb + (size_t)wid * 256)[lane] = r;
}

__global__ void k_gather128(const f16* __restrict__ f, const float* __restrict__ dis,
                            const int* __restrict__ rowptr, const int* __restrict__ e_src,
                            const float* __restrict__ bias, float* __restrict__ outb, int n) {
    int wid = (int)(((long long)blockIdx.x * blockDim.x + threadIdx.x) >> 6);
    int lane = threadIdx.x & 63;
    if (wid >= n) return;
    float dj = dis[wid];
    int r0 = rowptr[wid], r1 = rowptr[wid + 1];
    int deg = r1 - r0;
    int si = 0; float wi = 0.f;
    if (lane < deg) { si = e_src[r0 + lane]; wi = dis[si]; }
    f16x2 a = reinterpret_cast<const f16x2*>(f + (size_t)wid * 128)[lane];
    float ws = dj * dj;
    float ax = (float)a[0] * ws, ay = (float)a[1] * ws;
    int n64 = deg < 64 ? deg : 64;
    int e = 0;
    for (; e + 4 <= n64; e += 4) {
        int s0 = __shfl(si, e + 0), s1 = __shfl(si, e + 1);
        int s2 = __shfl(si, e + 2), s3 = __shfl(si, e + 3);
        float w0 = __shfl(wi, e + 0) * dj, w1 = __shfl(wi, e + 1) * dj;
        float w2 = __shfl(wi, e + 2) * dj, w3 = __shfl(wi, e + 3) * dj;
        f16x2 u0 = reinterpret_cast<const f16x2*>(f + (size_t)s0 * 128)[lane];
        f16x2 u1 = reinterpret_cast<const f16x2*>(f + (size_t)s1 * 128)[lane];
        f16x2 u2 = reinterpret_cast<const f16x2*>(f + (size_t)s2 * 128)[lane];
        f16x2 u3 = reinterpret_cast<const f16x2*>(f + (size_t)s3 * 128)[lane];
        ax += (float)u0[0] * w0 + (float)u1[0] * w1 + (float)u2[0] * w2 + (float)u3[0] * w3;
        ay += (float)u0[1] * w0 + (float)u1[1] * w1 + (float)u2[1] * w2 + (float)u3[1] * w3;
    }
    for (; e < n64; ++e) {
        int s0 = __shfl(si, e); float w0 = __shfl(wi, e) * dj;
        f16x2 u0 = reinterpret_cast<const f16x2*>(f + (size_t)s0 * 128)[lane];
        ax += (float)u0[0] * w0; ay += (float)u0[1] * w0;
    }
    for (int e2 = r0 + 64; e2 < r1; ++e2) {
        int s0 = __builtin_amdgcn_readfirstlane(e_src[e2]);
        float w0 = dis[s0] * dj;
        f16x2 u0 = reinterpret_cast<const f16x2*>(f + (size_t)s0 * 128)[lane];
        ax += (float)u0[0] * w0; ay += (float)u0[1] * w0;
    }
    float2 bb = reinterpret_cast<const float2*>(bias)[lane];
    reinterpret_cast<float2*>(outb + (size_t)wid * 128)[lane] = make_float2(ax + bb.x, ay + bb.y);
}

extern "C" void kernel_launch(void* const* d_in, const int* in_sizes, int n_in,
                              void* d_out, int out_size, void* d_ws, size_t ws_size,
                              hipStream_t stream) {
    const float* x1  = (const float*)d_in[0];
    const float* x2  = (const float*)d_in[1];
    const float* x3  = (const float*)d_in[2];
    const float* Wp1 = (const float*)d_in[3];
    const float* bp1 = (const float*)d_in[4];
    const float* Wp2 = (const float*)d_in[5];
    const float* bp2 = (const float*)d_in[6];
    const float* Wp3 = (const float*)d_in[7];
    const float* bp3 = (const float*)d_in[8];
    const float* W1  = (const float*)d_in[9];
    const float* b1  = (const float*)d_in[10];
    const float* W2  = (const float*)d_in[11];
    const float* b2  = (const float*)d_in[12];
    const int*   ei  = (const int*)d_in[13];
    const int* src = ei;
    const int* dst = ei + EE;
    float* out = (float*)d_out;

    // workspace (~137 MB)
    char* ws = (char*)d_ws;
    size_t off = 0;
    auto alloc = [&](size_t bytes) {
        char* p = ws + off;
        off += (bytes + 511) & ~(size_t)511;
        return p;
    };
    float* dis    = (float*)alloc((size_t)NT * 4);
    int*   cnt    = (int*)alloc((size_t)NT * 4);
    int*   cursor = (int*)alloc((size_t)NT * 4);
    int*   rowptr = (int*)alloc((size_t)(NT + 1) * 4);
    int*   part   = (int*)alloc(256 * 4);
    int*   e_src  = (int*)alloc((size_t)EE * 4);
    f16*   slotX  = (f16*)alloc((size_t)NT * 256 * 2);   // x16, then h16
    f16*   slotY  = (f16*)alloc((size_t)NT * 256 * 2);   // agg16, then hw216
    f16*   xc     = (f16*)alloc((size_t)(NN1 * 128 + NN2 * 256 + NN3 * 64) * 2);
    f16*   Wp1T   = (f16*)alloc((size_t)256 * 128 * 2);
    f16*   Wp2T   = (f16*)alloc((size_t)256 * 256 * 2);
    f16*   Wp3T   = (f16*)alloc((size_t)256 * 64 * 2);
    f16*   W1T    = (f16*)alloc((size_t)256 * 256 * 2);
    f16*   W2T    = (f16*)alloc((size_t)128 * 256 * 2);

    f16* x1c = xc;
    f16* x2c = xc + (size_t)NN1 * 128;
    f16* x3c = xc + (size_t)NN1 * 128 + (size_t)NN2 * 256;
    f16* x16   = slotX;
    f16* agg16 = slotY;
    f16* h16   = slotX;
    f16* hw216 = slotY;

    const int nb = cdiv(NT, 1024);

    // 0) CSR build + dis  (cnt & cursor zeroed by one memset: adjacent allocs)
    size_t zspan = (size_t)((char*)rowptr - (char*)cnt);
    hipMemsetAsync(cnt, 0, zspan, stream);
    k_hist<<<cdiv(EE, 256), 256, 0, stream>>>(dst, cnt, EE);
    k_scan1<<<nb, 256, 0, stream>>>(cnt, rowptr, part, dis, NT);
    k_scan2<<<1, 256, 0, stream>>>(part, nb);
    k_scan3<<<cdiv(NT, 256), 256, 0, stream>>>(rowptr, part, NT, EE);
    k_fill<<<cdiv(EE, 256), 256, 0, stream>>>(src, dst, rowptr, cursor, e_src, EE);

    // 1) dtype prep (merged)
    {
        int na4 = NN1 * 128 / 4, nb4 = NN2 * 256 / 4, nc4 = NN3 * 64 / 4;
        k_cvt_all<<<cdiv(na4 + nb4 + nc4, 256), 256, 0, stream>>>(x1, na4, x2, nb4, x3, nc4, xc);
        TArgs t = {Wp1, Wp2, Wp3, W1, W2, Wp1T, Wp2T, Wp3T, W1T, W2T};
        k_transpose_all<<<cdiv(212992, 256), 256, 0, stream>>>(t);
    }

    // 2) projections -> x16
    {
        dim3 g1(cdiv(NN1, 128), 2);
        k_hgemm<false, true><<<g1, 256, 0, stream>>>(x1c, Wp1T, bp1, x16, NN1, 128, 256);
        dim3 g2(cdiv(NN2, 128), 2);
        k_hgemm<false, true><<<g2, 256, 0, stream>>>(x2c, Wp2T, bp2, x16 + (size_t)NN1 * 256, NN2, 256, 256);
        dim3 g3(cdiv(NN3, 128), 2);
        k_hgemm<false, true><<<g3, 256, 0, stream>>>(x3c, Wp3T, bp3, x16 + (size_t)(NN1 + NN2) * 256, NN3, 64, 256);
    }

    // 3) agg16 = Â x16
    k_gather256<<<cdiv(NT * 64, 256), 256, 0, stream>>>(x16, dis, rowptr, e_src, agg16, NT);

    // 4) h16 = relu(agg16 @ W1 + b1)
    {
        dim3 g(cdiv(NT, 128), 2);
        k_hgemm<true, true><<<g, 256, 0, stream>>>(agg16, W1T, b1, h16, NT, 256, 256);
    }

    // 5) hw216 = h16 @ W2
    {
        dim3 g(cdiv(NT, 128), 1);
        k_hgemm<false, false><<<g, 256, 0, stream>>>(h16, W2T, nullptr, hw216, NT, 256, 128);
    }

    // 6) out = Â hw216 + b2  (f32 output)
    k_gather128<<<cdiv(NT * 64, 256), 256, 0, stream>>>(hw216, dis, rowptr, e_src, b2, out, NT);
}

// Round 8
// 313.384 us; speedup vs baseline: 13.2260x; 1.0569x over previous
//
#include <hip/hip_runtime.h>
#include <cstddef>

#define NT 100000
#define NN1 40000
#define NN2 30000
#define NN3 30000
#define EE 800000
#define DIN 256
#define DHID 256
#define DOUT 128

typedef _Float16 f16;
typedef f16 f16x8 __attribute__((ext_vector_type(8)));
typedef f16 f16x4 __attribute__((ext_vector_type(4)));
typedef float f32x4 __attribute__((ext_vector_type(4)));

static inline int cdiv(int a, int b) { return (a + b - 1) / b; }

// async global->LDS, 16B per lane; LDS dest = wave-uniform base + lane*16
__device__ __forceinline__ void gload_lds16(const f16* g, f16* l) {
    __builtin_amdgcn_global_load_lds(
        (const __attribute__((address_space(1))) void*)g,
        (__attribute__((address_space(3))) void*)l, 16, 0, 0);
}

// ---------------- CSR build (dst-sorted adjacency) --------------------------
__global__ void k_hist(const int* __restrict__ dst, int* __restrict__ cnt, int e) {
    int i = blockIdx.x * blockDim.x + threadIdx.x;
    if (i < e) atomicAdd(&cnt[dst[i]], 1);
}

// exclusive scan (phase 1) + dis = rsqrt(cnt+1) fused
__global__ void k_scan1(const int* __restrict__ cnt, int* __restrict__ rowptr,
                        int* __restrict__ part, float* __restrict__ dis, int n) {
    __shared__ int sums[256];
    int b = blockIdx.x, t = threadIdx.x;
    int base = b * 1024 + t * 4;
    int v0 = (base + 0 < n) ? cnt[base + 0] : 0;
    int v1 = (base + 1 < n) ? cnt[base + 1] : 0;
    int v2 = (base + 2 < n) ? cnt[base + 2] : 0;
    int v3 = (base + 3 < n) ? cnt[base + 3] : 0;
    if (base + 0 < n) dis[base + 0] = rsqrtf((float)v0 + 1.0f);
    if (base + 1 < n) dis[base + 1] = rsqrtf((float)v1 + 1.0f);
    if (base + 2 < n) dis[base + 2] = rsqrtf((float)v2 + 1.0f);
    if (base + 3 < n) dis[base + 3] = rsqrtf((float)v3 + 1.0f);
    int tsum = v0 + v1 + v2 + v3;
    sums[t] = tsum;
    __syncthreads();
    for (int off = 1; off < 256; off <<= 1) {
        int y = (t >= off) ? sums[t - off] : 0;
        __syncthreads();
        sums[t] += y;
        __syncthreads();
    }
    int excl = sums[t] - tsum;
    if (base + 0 < n) rowptr[base + 0] = excl;
    if (base + 1 < n) rowptr[base + 1] = excl + v0;
    if (base + 2 < n) rowptr[base + 2] = excl + v0 + v1;
    if (base + 3 < n) rowptr[base + 3] = excl + v0 + v1 + v2;
    if (t == 255) part[b] = sums[255];
}

__global__ void k_scan2(int* __restrict__ part, int nb) {
    __shared__ int sums[256];
    int t = threadIdx.x;
    int v = (t < nb) ? part[t] : 0;
    sums[t] = v;
    __syncthreads();
    for (int off = 1; off < 256; off <<= 1) {
        int y = (t >= off) ? sums[t - off] : 0;
        __syncthreads();
        sums[t] += y;
        __syncthreads();
    }
    if (t < nb) part[t] = sums[t] - v;
}

__global__ void k_scan3(int* __restrict__ rowptr, const int* __restrict__ part,
                        int n, int total) {
    int i = blockIdx.x * blockDim.x + threadIdx.x;
    if (i < n) rowptr[i] += part[i >> 10];
    if (i == 0) rowptr[n] = total;
}

// fill CSR with (src, w=dis[src]*dis[dst]) pairs — weights precomputed ONCE,
// consumed by BOTH gather layers (kills the dependent dis[] gather there)
__global__ void k_fill(const int* __restrict__ src, const int* __restrict__ dst,
                       const float* __restrict__ dis, const int* __restrict__ rowptr,
                       int* __restrict__ cursor, int2* __restrict__ e_pairs, int e) {
    int i = blockIdx.x * blockDim.x + threadIdx.x;
    if (i >= e) return;
    int s = src[i], t = dst[i];
    int pos = atomicAdd(&cursor[t], 1);
    int2 p;
    p.x = s;
    p.y = __float_as_int(dis[s] * dis[t]);
    e_pairs[rowptr[t] + pos] = p;
}

// ---------------- dtype prep (merged) ---------------------------------------
__global__ void k_cvt_all(const float* __restrict__ a, int na4,
                          const float* __restrict__ b, int nb4,
                          const float* __restrict__ c, int nc4,
                          f16* __restrict__ o) {
    int i = blockIdx.x * blockDim.x + threadIdx.x;
    const float* s; int j;
    if (i < na4) { s = a; j = i; }
    else if (i < na4 + nb4) { s = b; j = i - na4; }
    else if (i < na4 + nb4 + nc4) { s = c; j = i - na4 - nb4; }
    else return;
    float4 v = reinterpret_cast<const float4*>(s)[j];
    f16x4 r = {(f16)v.x, (f16)v.y, (f16)v.z, (f16)v.w};
    reinterpret_cast<f16x4*>(o)[i] = r;
}

struct TArgs {
    const float *W0, *W1, *W2, *W3, *W4;
    f16 *T0, *T1, *T2, *T3, *T4;
};
__global__ void k_transpose_all(TArgs t) {
    int i = blockIdx.x * blockDim.x + threadIdx.x;
    const float* W; f16* T; int K, N, j;
    if      (i <  32768) { W = t.W0; T = t.T0; K = 128; N = 256; j = i; }
    else if (i <  98304) { W = t.W1; T = t.T1; K = 256; N = 256; j = i - 32768; }
    else if (i < 114688) { W = t.W2; T = t.T2; K =  64; N = 256; j = i - 98304; }
    else if (i < 180224) { W = t.W3; T = t.T3; K = 256; N = 256; j = i - 114688; }
    else if (i < 212992) { W = t.W4; T = t.T4; K = 256; N = 128; j = i - 180224; }
    else return;
    int k = j / N, n = j - k * N;
    T[n * K + k] = (f16)W[j];
}

// ---------------- f16 MFMA GEMM body (shared by k_hgemm / k_proj3) ----------
// C[M,N](f16) = A[M,K](f16) @ BT[N,K]^T (+bias,+relu). 128x128 tile, BK=32,
// 256 thr = 4 waves (2x2). LDS slot swizzle: slot = ch ^ ((row>>1)&3) -> 2-way
// banks on ds_read_b128 (free). gload_lds dest linear; swizzle applied on the
// per-lane GLOBAL source address (rule #21). As/Bs: 8192 f16 each (2 bufs).
template<bool RELU_OUT, bool HAS_BIAS>
__device__ __forceinline__
void hgemm_body(f16* As, f16* Bs,
                const f16* __restrict__ A, const f16* __restrict__ BT,
                const float* __restrict__ bias, f16* __restrict__ C,
                int M, int K, int N, int bx, int by) {
    const int tid = threadIdx.x;
    const int lane = tid & 63;
    const int wid = tid >> 6;
    const int wm = wid & 1, wn = wid >> 1;
    const int bm = bx * 128;
    const int bn = by * 128;
    const int r15 = lane & 15, g = lane >> 4;
    const int sr  = lane >> 2;
    const int chs = (lane & 3) ^ ((lane >> 3) & 3);

    auto stage = [&](int buf, int k0) {
        #pragma unroll
        for (int q = 0; q < 2; ++q) {
            int chunk = wid + q * 4;
            int row = chunk * 16 + sr;
            int ga = bm + row; if (ga >= M) ga = M - 1;
            gload_lds16(A  + (size_t)ga * K + k0 + chs * 8, As + buf * 4096 + chunk * 512);
            gload_lds16(BT + (size_t)(bn + row) * K + k0 + chs * 8, Bs + buf * 4096 + chunk * 512);
        }
    };

    f32x4 acc[4][4] = {};
    const int nsteps = K >> 5;
    stage(0, 0);
    __syncthreads();
    int cur = 0;
    for (int step = 0; step < nsteps; ++step) {
        if (step + 1 < nsteps) stage(cur ^ 1, (step + 1) << 5);
        f16x8 af[4], bf[4];
        const int sl = (g ^ ((r15 >> 1) & 3)) * 8;
        #pragma unroll
        for (int mf = 0; mf < 4; ++mf) {
            int row = wm * 64 + mf * 16 + r15;
            af[mf] = *reinterpret_cast<const f16x8*>(As + cur * 4096 + row * 32 + sl);
        }
        #pragma unroll
        for (int nf = 0; nf < 4; ++nf) {
            int row = wn * 64 + nf * 16 + r15;
            bf[nf] = *reinterpret_cast<const f16x8*>(Bs + cur * 4096 + row * 32 + sl);
        }
        #pragma unroll
        for (int mf = 0; mf < 4; ++mf)
            #pragma unroll
            for (int nf = 0; nf < 4; ++nf)
                acc[mf][nf] = __builtin_amdgcn_mfma_f32_16x16x32_f16(af[mf], bf[nf], acc[mf][nf], 0, 0, 0);
        __syncthreads();
        cur ^= 1;
    }

    #pragma unroll
    for (int mf = 0; mf < 4; ++mf) {
        #pragma unroll
        for (int nf = 0; nf < 4; ++nf) {
            int col = bn + wn * 64 + nf * 16 + r15;
            float bv = HAS_BIAS ? bias[col] : 0.f;
            #pragma unroll
            for (int r = 0; r < 4; ++r) {
                int rowg = bm + wm * 64 + mf * 16 + g * 4 + r;
                if (rowg < M) {
                    float v = acc[mf][nf][r] + bv;
                    if (RELU_OUT) v = fmaxf(v, 0.f);
                    C[(size_t)rowg * N + col] = (f16)v;
                }
            }
        }
    }
}

template<bool RELU_OUT, bool HAS_BIAS>
__global__ __launch_bounds__(256)
void k_hgemm(const f16* __restrict__ A, const f16* __restrict__ BT,
             const float* __restrict__ bias, f16* __restrict__ C,
             int M, int K, int N) {
    extern __shared__ f16 smem[];
    hgemm_body<RELU_OUT, HAS_BIAS>(smem, smem + 8192, A, BT, bias, C, M, K, N,
                                   blockIdx.x, blockIdx.y);
}

// 3 projections packed into one dispatch (segment switch on blockIdx.x)
struct P3 {
    const f16 *a1, *a2, *a3, *t1, *t2, *t3;
    const float *b1, *b2, *b3;
    f16 *o1, *o2, *o3;
    int g1, g2;
};
__global__ __launch_bounds__(256) void k_proj3(P3 p) {
    extern __shared__ f16 smem[];
    int bx = blockIdx.x, by = blockIdx.y;
    if (bx < p.g1)
        hgemm_body<false, true>(smem, smem + 8192, p.a1, p.t1, p.b1, p.o1, NN1, 128, 256, bx, by);
    else if (bx < p.g1 + p.g2)
        hgemm_body<false, true>(smem, smem + 8192, p.a2, p.t2, p.b2, p.o2, NN2, 256, 256, bx - p.g1, by);
    else
        hgemm_body<false, true>(smem, smem + 8192, p.a3, p.t3, p.b3, p.o3, NN3, 64, 256, bx - p.g1 - p.g2, by);
}

// ---------------- gathers: half-wave per node, precomputed edge weights -----
// D=256: 32 lanes x f16x8 (16B) = 512B row. One independent 8B pair load per
// lane, shfl-broadcast within the 32-lane group. 2 nodes per wave.
__global__ void k_gather256(const f16* __restrict__ f, const float* __restrict__ dis,
                            const int* __restrict__ rowptr, const int2* __restrict__ e_pairs,
                            f16* __restrict__ outb, int n) {
    int node = (int)(((long long)blockIdx.x * blockDim.x + threadIdx.x) >> 5);
    int l = threadIdx.x & 31;
    if (node >= n) return;
    float dj = dis[node];
    int r0 = rowptr[node], r1 = rowptr[node + 1];
    int deg = r1 - r0;
    int si = 0; float wi = 0.f;
    if (l < deg) { int2 p = e_pairs[r0 + l]; si = p.x; wi = __int_as_float(p.y); }
    f16x8 a = reinterpret_cast<const f16x8*>(f + (size_t)node * 256)[l];
    float ws = dj * dj;
    float acc[8];
    #pragma unroll
    for (int k = 0; k < 8; ++k) acc[k] = (float)a[k] * ws;
    int n32 = deg < 32 ? deg : 32;
    int e = 0;
    for (; e + 4 <= n32; e += 4) {
        int s0 = __shfl(si, e + 0, 32), s1 = __shfl(si, e + 1, 32);
        int s2 = __shfl(si, e + 2, 32), s3 = __shfl(si, e + 3, 32);
        float w0 = __shfl(wi, e + 0, 32), w1 = __shfl(wi, e + 1, 32);
        float w2 = __shfl(wi, e + 2, 32), w3 = __shfl(wi, e + 3, 32);
        f16x8 u0 = reinterpret_cast<const f16x8*>(f + (size_t)s0 * 256)[l];
        f16x8 u1 = reinterpret_cast<const f16x8*>(f + (size_t)s1 * 256)[l];
        f16x8 u2 = reinterpret_cast<const f16x8*>(f + (size_t)s2 * 256)[l];
        f16x8 u3 = reinterpret_cast<const f16x8*>(f + (size_t)s3 * 256)[l];
        #pragma unroll
        for (int k = 0; k < 8; ++k)
            acc[k] += (float)u0[k] * w0 + (float)u1[k] * w1 + (float)u2[k] * w2 + (float)u3[k] * w3;
    }
    for (; e < n32; ++e) {
        int s0 = __shfl(si, e, 32);
        float w0 = __shfl(wi, e, 32);
        f16x8 u0 = reinterpret_cast<const f16x8*>(f + (size_t)s0 * 256)[l];
        #pragma unroll
        for (int k = 0; k < 8; ++k) acc[k] += (float)u0[k] * w0;
    }
    for (int e2 = r0 + 32; e2 < r1; ++e2) {          // deg>32 tail (rare)
        int2 p = e_pairs[e2];                         // uniform addr -> broadcast
        float w0 = __int_as_float(p.y);
        f16x8 u0 = reinterpret_cast<const f16x8*>(f + (size_t)p.x * 256)[l];
        #pragma unroll
        for (int k = 0; k < 8; ++k) acc[k] += (float)u0[k] * w0;
    }
    f16x8 r;
    #pragma unroll
    for (int k = 0; k < 8; ++k) r[k] = (f16)acc[k];
    reinterpret_cast<f16x8*>(outb + (size_t)node * 256)[l] = r;
}

// D=128: 32 lanes x f16x4 (8B) = 256B row; f32 out + bias (float4/lane write)
__global__ void k_gather128(const f16* __restrict__ f, const float* __restrict__ dis,
                            const int* __restrict__ rowptr, const int2* __restrict__ e_pairs,
                            const float* __restrict__ bias, float* __restrict__ outb, int n) {
    int node = (int)(((long long)blockIdx.x * blockDim.x + threadIdx.x) >> 5);
    int l = threadIdx.x & 31;
    if (node >= n) return;
    float dj = dis[node];
    int r0 = rowptr[node], r1 = rowptr[node + 1];
    int deg = r1 - r0;
    int si = 0; float wi = 0.f;
    if (l < deg) { int2 p = e_pairs[r0 + l]; si = p.x; wi = __int_as_float(p.y); }
    f16x4 a = reinterpret_cast<const f16x4*>(f + (size_t)node * 128)[l];
    float ws = dj * dj;
    float acc[4];
    #pragma unroll
    for (int k = 0; k < 4; ++k) acc[k] = (float)a[k] * ws;
    int n32 = deg < 32 ? deg : 32;
    int e = 0;
    for (; e + 4 <= n32; e += 4) {
        int s0 = __shfl(si, e + 0, 32), s1 = __shfl(si, e + 1, 32);
        int s2 = __shfl(si, e + 2, 32), s3 = __shfl(si, e + 3, 32);
        float w0 = __shfl(wi, e + 0, 32), w1 = __shfl(wi, e + 1, 32);
        float w2 = __shfl(wi, e + 2, 32), w3 = __shfl(wi, e + 3, 32);
        f16x4 u0 = reinterpret_cast<const f16x4*>(f + (size_t)s0 * 128)[l];
        f16x4 u1 = reinterpret_cast<const f16x4*>(f + (size_t)s1 * 128)[l];
        f16x4 u2 = reinterpret_cast<const f16x4*>(f + (size_t)s2 * 128)[l];
        f16x4 u3 = reinterpret_cast<const f16x4*>(f + (size_t)s3 * 128)[l];
        #pragma unroll
        for (int k = 0; k < 4; ++k)
            acc[k] += (float)u0[k] * w0 + (float)u1[k] * w1 + (float)u2[k] * w2 + (float)u3[k] * w3;
    }
    for (; e < n32; ++e) {
        int s0 = __shfl(si, e, 32);
        float w0 = __shfl(wi, e, 32);
        f16x4 u0 = reinterpret_cast<const f16x4*>(f + (size_t)s0 * 128)[l];
        #pragma unroll
        for (int k = 0; k < 4; ++k) acc[k] += (float)u0[k] * w0;
    }
    for (int e2 = r0 + 32; e2 < r1; ++e2) {
        int2 p = e_pairs[e2];
        float w0 = __int_as_float(p.y);
        f16x4 u0 = reinterpret_cast<const f16x4*>(f + (size_t)p.x * 128)[l];
        #pragma unroll
        for (int k = 0; k < 4; ++k) acc[k] += (float)u0[k] * w0;
    }
    float4 bb = reinterpret_cast<const float4*>(bias)[l];
    float4 r = make_float4(acc[0] + bb.x, acc[1] + bb.y, acc[2] + bb.z, acc[3] + bb.w);
    reinterpret_cast<float4*>(outb + (size_t)node * 128)[l] = r;
}

extern "C" void kernel_launch(void* const* d_in, const int* in_sizes, int n_in,
                              void* d_out, int out_size, void* d_ws, size_t ws_size,
                              hipStream_t stream) {
    const float* x1  = (const float*)d_in[0];
    const float* x2  = (const float*)d_in[1];
    const float* x3  = (const float*)d_in[2];
    const float* Wp1 = (const float*)d_in[3];
    const float* bp1 = (const float*)d_in[4];
    const float* Wp2 = (const float*)d_in[5];
    const float* bp2 = (const float*)d_in[6];
    const float* Wp3 = (const float*)d_in[7];
    const float* bp3 = (const float*)d_in[8];
    const float* W1  = (const float*)d_in[9];
    const float* b1  = (const float*)d_in[10];
    const float* W2  = (const float*)d_in[11];
    const float* b2  = (const float*)d_in[12];
    const int*   ei  = (const int*)d_in[13];
    const int* src = ei;
    const int* dst = ei + EE;
    float* out = (float*)d_out;

    // workspace (~143 MB)
    char* ws = (char*)d_ws;
    size_t off = 0;
    auto alloc = [&](size_t bytes) {
        char* p = ws + off;
        off += (bytes + 511) & ~(size_t)511;
        return p;
    };
    float* dis    = (float*)alloc((size_t)NT * 4);
    int*   cnt    = (int*)alloc((size_t)NT * 4);
    int*   cursor = (int*)alloc((size_t)NT * 4);
    int*   rowptr = (int*)alloc((size_t)(NT + 1) * 4);
    int*   part   = (int*)alloc(256 * 4);
    int2*  e_pairs= (int2*)alloc((size_t)EE * 8);
    f16*   slotX  = (f16*)alloc((size_t)NT * 256 * 2);
    f16*   slotY  = (f16*)alloc((size_t)NT * 256 * 2);
    f16*   xc     = (f16*)alloc((size_t)(NN1 * 128 + NN2 * 256 + NN3 * 64) * 2);
    f16*   Wp1T   = (f16*)alloc((size_t)256 * 128 * 2);
    f16*   Wp2T   = (f16*)alloc((size_t)256 * 256 * 2);
    f16*   Wp3T   = (f16*)alloc((size_t)256 * 64 * 2);
    f16*   W1T    = (f16*)alloc((size_t)256 * 256 * 2);
    f16*   W2T    = (f16*)alloc((size_t)128 * 256 * 2);

    f16* x1c = xc;
    f16* x2c = xc + (size_t)NN1 * 128;
    f16* x3c = xc + (size_t)NN1 * 128 + (size_t)NN2 * 256;
    f16* x16   = slotX;
    f16* agg16 = slotY;
    f16* h16   = slotX;
    f16* hw216 = slotY;

    const int nb = cdiv(NT, 1024);

    // 0) CSR build + dis + per-edge weights
    size_t zspan = (size_t)((char*)rowptr - (char*)cnt);   // zero cnt+cursor
    hipMemsetAsync(cnt, 0, zspan, stream);
    k_hist<<<cdiv(EE, 256), 256, 0, stream>>>(dst, cnt, EE);
    k_scan1<<<nb, 256, 0, stream>>>(cnt, rowptr, part, dis, NT);
    k_scan2<<<1, 256, 0, stream>>>(part, nb);
    k_scan3<<<cdiv(NT, 256), 256, 0, stream>>>(rowptr, part, NT, EE);
    k_fill<<<cdiv(EE, 256), 256, 0, stream>>>(src, dst, dis, rowptr, cursor, e_pairs, EE);

    // 1) dtype prep (merged)
    {
        int na4 = NN1 * 128 / 4, nb4 = NN2 * 256 / 4, nc4 = NN3 * 64 / 4;
        k_cvt_all<<<cdiv(na4 + nb4 + nc4, 256), 256, 0, stream>>>(x1, na4, x2, nb4, x3, nc4, xc);
        TArgs t = {Wp1, Wp2, Wp3, W1, W2, Wp1T, Wp2T, Wp3T, W1T, W2T};
        k_transpose_all<<<cdiv(212992, 256), 256, 0, stream>>>(t);
    }

    // 2) projections -> x16 (one packed dispatch)
    {
        P3 p = {x1c, x2c, x3c, Wp1T, Wp2T, Wp3T, bp1, bp2, bp3,
                x16, x16 + (size_t)NN1 * 256, x16 + (size_t)(NN1 + NN2) * 256,
                cdiv(NN1, 128), cdiv(NN2, 128)};
        dim3 g(cdiv(NN1, 128) + cdiv(NN2, 128) + cdiv(NN3, 128), 2);
        k_proj3<<<g, 256, 32768, stream>>>(p);
    }

    // 3) agg16 = Â x16
    k_gather256<<<cdiv(NT * 32, 256), 256, 0, stream>>>(x16, dis, rowptr, e_pairs, agg16, NT);

    // 4) h16 = relu(agg16 @ W1 + b1)
    {
        dim3 g(cdiv(NT, 128), 2);
        k_hgemm<true, true><<<g, 256, 32768, stream>>>(agg16, W1T, b1, h16, NT, 256, 256);
    }

    // 5) hw216 = h16 @ W2
    {
        dim3 g(cdiv(NT, 128), 1);
        k_hgemm<false, false><<<g, 256, 32768, stream>>>(h16, W2T, nullptr, hw216, NT, 256, 128);
    }

    // 6) out = Â hw216 + b2  (f32 output)
    k_gather128<<<cdiv(NT * 32, 256), 256, 0, stream>>>(hw216, dis, rowptr, e_pairs, b2, out, NT);
}

// Round 9
// 309.836 us; speedup vs baseline: 13.3775x; 1.0115x over previous
//
#include <hip/hip_runtime.h>
#include <cstddef>

#define NT 100000
#define NN1 40000
#define NN2 30000
#define NN3 30000
#define EE 800000

typedef _Float16 f16;
typedef f16 f16x8 __attribute__((ext_vector_type(8)));
typedef f16 f16x4 __attribute__((ext_vector_type(4)));
typedef float f32x4 __attribute__((ext_vector_type(4)));

static inline int cdiv(int a, int b) { return (a + b - 1) / b; }

// async global->LDS, 16B per lane
__device__ __forceinline__ void gload_lds16(const f16* g, f16* l) {
    __builtin_amdgcn_global_load_lds(
        (const __attribute__((address_space(1))) void*)g,
        (__attribute__((address_space(3))) void*)l, 16, 0, 0);
}

// ---------------- CSR build (dst-sorted adjacency) --------------------------
__global__ void k_hist(const int* __restrict__ dst, int* __restrict__ cnt, int e) {
    int i = blockIdx.x * blockDim.x + threadIdx.x;
    if (i < e) atomicAdd(&cnt[dst[i]], 1);
}

__global__ void k_scan1(const int* __restrict__ cnt, int* __restrict__ rowptr,
                        int* __restrict__ part, float* __restrict__ dis, int n) {
    __shared__ int sums[256];
    int b = blockIdx.x, t = threadIdx.x;
    int base = b * 1024 + t * 4;
    int v0 = (base + 0 < n) ? cnt[base + 0] : 0;
    int v1 = (base + 1 < n) ? cnt[base + 1] : 0;
    int v2 = (base + 2 < n) ? cnt[base + 2] : 0;
    int v3 = (base + 3 < n) ? cnt[base + 3] : 0;
    if (base + 0 < n) dis[base + 0] = rsqrtf((float)v0 + 1.0f);
    if (base + 1 < n) dis[base + 1] = rsqrtf((float)v1 + 1.0f);
    if (base + 2 < n) dis[base + 2] = rsqrtf((float)v2 + 1.0f);
    if (base + 3 < n) dis[base + 3] = rsqrtf((float)v3 + 1.0f);
    int tsum = v0 + v1 + v2 + v3;
    sums[t] = tsum;
    __syncthreads();
    for (int off = 1; off < 256; off <<= 1) {
        int y = (t >= off) ? sums[t - off] : 0;
        __syncthreads();
        sums[t] += y;
        __syncthreads();
    }
    int excl = sums[t] - tsum;
    if (base + 0 < n) rowptr[base + 0] = excl;
    if (base + 1 < n) rowptr[base + 1] = excl + v0;
    if (base + 2 < n) rowptr[base + 2] = excl + v0 + v1;
    if (base + 3 < n) rowptr[base + 3] = excl + v0 + v1 + v2;
    if (t == 255) part[b] = sums[255];
}

__global__ void k_scan2(int* __restrict__ part, int nb) {
    __shared__ int sums[256];
    int t = threadIdx.x;
    int v = (t < nb) ? part[t] : 0;
    sums[t] = v;
    __syncthreads();
    for (int off = 1; off < 256; off <<= 1) {
        int y = (t >= off) ? sums[t - off] : 0;
        __syncthreads();
        sums[t] += y;
        __syncthreads();
    }
    if (t < nb) part[t] = sums[t] - v;
}

__global__ void k_scan3(int* __restrict__ rowptr, const int* __restrict__ part,
                        int n, int total) {
    int i = blockIdx.x * blockDim.x + threadIdx.x;
    if (i < n) rowptr[i] += part[i >> 10];
    if (i == 0) rowptr[n] = total;
}

// CSR payload: (src, w=dis[src]*dis[dst]) — used by fused layer1 AND gather128
__global__ void k_fill(const int* __restrict__ src, const int* __restrict__ dst,
                       const float* __restrict__ dis, const int* __restrict__ rowptr,
                       int* __restrict__ cursor, int2* __restrict__ e_pairs, int e) {
    int i = blockIdx.x * blockDim.x + threadIdx.x;
    if (i >= e) return;
    int s = src[i], t = dst[i];
    int pos = atomicAdd(&cursor[t], 1);
    int2 p;
    p.x = s;
    p.y = __float_as_int(dis[s] * dis[t]);
    e_pairs[rowptr[t] + pos] = p;
}

// ---------------- dtype prep (merged) ---------------------------------------
__global__ void k_cvt_all(const float* __restrict__ a, int na4,
                          const float* __restrict__ b, int nb4,
                          const float* __restrict__ c, int nc4,
                          f16* __restrict__ o) {
    int i = blockIdx.x * blockDim.x + threadIdx.x;
    const float* s; int j;
    if (i < na4) { s = a; j = i; }
    else if (i < na4 + nb4) { s = b; j = i - na4; }
    else if (i < na4 + nb4 + nc4) { s = c; j = i - na4 - nb4; }
    else return;
    float4 v = reinterpret_cast<const float4*>(s)[j];
    f16x4 r = {(f16)v.x, (f16)v.y, (f16)v.z, (f16)v.w};
    reinterpret_cast<f16x4*>(o)[i] = r;
}

struct TArgs {
    const float *W0, *W1, *W2, *W3, *W4;
    f16 *T0, *T1, *T2, *T3, *T4;
};
__global__ void k_transpose_all(TArgs t) {
    int i = blockIdx.x * blockDim.x + threadIdx.x;
    const float* W; f16* T; int K, N, j;
    if      (i <  32768) { W = t.W0; T = t.T0; K = 128; N = 256; j = i; }
    else if (i <  98304) { W = t.W1; T = t.T1; K = 256; N = 256; j = i - 32768; }
    else if (i < 114688) { W = t.W2; T = t.T2; K =  64; N = 256; j = i - 98304; }
    else if (i < 180224) { W = t.W3; T = t.T3; K = 256; N = 256; j = i - 114688; }
    else if (i < 212992) { W = t.W4; T = t.T4; K = 256; N = 128; j = i - 180224; }
    else return;
    int k = j / N, n = j - k * N;
    T[n * K + k] = (f16)W[j];
}

// ---------------- projection GEMM (128x128 tile, gload_lds dbuf) ------------
template<bool RELU_OUT, bool HAS_BIAS>
__device__ __forceinline__
void hgemm_body(f16* As, f16* Bs,
                const f16* __restrict__ A, const f16* __restrict__ BT,
                const float* __restrict__ bias, f16* __restrict__ C,
                int M, int K, int N, int bx, int by) {
    const int tid = threadIdx.x;
    const int lane = tid & 63;
    const int wid = tid >> 6;
    const int wm = wid & 1, wn = wid >> 1;
    const int bm = bx * 128;
    const int bn = by * 128;
    const int r15 = lane & 15, g = lane >> 4;
    const int sr  = lane >> 2;
    const int chs = (lane & 3) ^ ((lane >> 3) & 3);

    auto stage = [&](int buf, int k0) {
        #pragma unroll
        for (int q = 0; q < 2; ++q) {
            int chunk = wid + q * 4;
            int row = chunk * 16 + sr;
            int ga = bm + row; if (ga >= M) ga = M - 1;
            gload_lds16(A  + (size_t)ga * K + k0 + chs * 8, As + buf * 4096 + chunk * 512);
            gload_lds16(BT + (size_t)(bn + row) * K + k0 + chs * 8, Bs + buf * 4096 + chunk * 512);
        }
    };

    f32x4 acc[4][4] = {};
    const int nsteps = K >> 5;
    stage(0, 0);
    __syncthreads();
    int cur = 0;
    for (int step = 0; step < nsteps; ++step) {
        if (step + 1 < nsteps) stage(cur ^ 1, (step + 1) << 5);
        f16x8 af[4], bf[4];
        const int sl = (g ^ ((r15 >> 1) & 3)) * 8;
        #pragma unroll
        for (int mf = 0; mf < 4; ++mf) {
            int row = wm * 64 + mf * 16 + r15;
            af[mf] = *reinterpret_cast<const f16x8*>(As + cur * 4096 + row * 32 + sl);
        }
        #pragma unroll
        for (int nf = 0; nf < 4; ++nf) {
            int row = wn * 64 + nf * 16 + r15;
            bf[nf] = *reinterpret_cast<const f16x8*>(Bs + cur * 4096 + row * 32 + sl);
        }
        #pragma unroll
        for (int mf = 0; mf < 4; ++mf)
            #pragma unroll
            for (int nf = 0; nf < 4; ++nf)
                acc[mf][nf] = __builtin_amdgcn_mfma_f32_16x16x32_f16(af[mf], bf[nf], acc[mf][nf], 0, 0, 0);
        __syncthreads();
        cur ^= 1;
    }

    #pragma unroll
    for (int mf = 0; mf < 4; ++mf) {
        #pragma unroll
        for (int nf = 0; nf < 4; ++nf) {
            int col = bn + wn * 64 + nf * 16 + r15;
            float bv = HAS_BIAS ? bias[col] : 0.f;
            #pragma unroll
            for (int r = 0; r < 4; ++r) {
                int rowg = bm + wm * 64 + mf * 16 + g * 4 + r;
                if (rowg < M) {
                    float v = acc[mf][nf][r] + bv;
                    if (RELU_OUT) v = fmaxf(v, 0.f);
                    C[(size_t)rowg * N + col] = (f16)v;
                }
            }
        }
    }
}

struct P3 {
    const f16 *a1, *a2, *a3, *t1, *t2, *t3;
    const float *b1, *b2, *b3;
    f16 *o1, *o2, *o3;
    int g1, g2;
};
__global__ __launch_bounds__(256) void k_proj3(P3 p) {
    extern __shared__ f16 smem[];
    int bx = blockIdx.x, by = blockIdx.y;
    if (bx < p.g1)
        hgemm_body<false, true>(smem, smem + 8192, p.a1, p.t1, p.b1, p.o1, NN1, 128, 256, bx, by);
    else if (bx < p.g1 + p.g2)
        hgemm_body<false, true>(smem, smem + 8192, p.a2, p.t2, p.b2, p.o2, NN2, 256, 256, bx - p.g1, by);
    else
        hgemm_body<false, true>(smem, smem + 8192, p.a3, p.t3, p.b3, p.o3, NN3, 64, 256, bx - p.g1 - p.g2, by);
}

// ---------------- FUSED: gather(Âx) -> GEMM1+ReLU -> GEMM2 ------------------
// Block = 64 dst nodes. LDS panel P = [64 rows][256 cols] f16, 32KB, stored as
// 8 subpanels of BK=32: f16 addr = s*2048 + row*32 + slot*8 + (col&7),
// slot = ((col>>3)&3) ^ ((row>>1)&3)  (XOR swizzle; matches frag-read pattern).
// W1T (128KB) and W2T (64KB) read directly from L2 as B-fragments.
__global__ __launch_bounds__(256)
void k_fused(const f16* __restrict__ x16, const float* __restrict__ dis,
             const int* __restrict__ rowptr, const int2* __restrict__ e_pairs,
             const f16* __restrict__ W1T, const float* __restrict__ b1,
             const f16* __restrict__ W2T, f16* __restrict__ hw2, int M) {
    __shared__ f16 P[64 * 256];
    const int tid = threadIdx.x;
    const int lane = tid & 63;
    const int bm = blockIdx.x * 64;

    // ---- phase 1: gather 64 agg-rows into P (reg accumulate, swizzled write)
    {
        const int grp = tid >> 5;     // 0..7
        const int l = tid & 31;       // lane-in-group: covers cols 8l..8l+7
        for (int it = 0; it < 8; ++it) {
            int row = it * 8 + grp;
            int node = bm + row;
            float av[8];
            if (node < M) {
                float dj = dis[node];
                int r0 = rowptr[node], r1 = rowptr[node + 1];
                int deg = r1 - r0;
                int si = 0; float wi = 0.f;
                if (l < deg) { int2 pr = e_pairs[r0 + l]; si = pr.x; wi = __int_as_float(pr.y); }
                f16x8 a = reinterpret_cast<const f16x8*>(x16 + (size_t)node * 256)[l];
                float wself = dj * dj;
                #pragma unroll
                for (int k = 0; k < 8; ++k) av[k] = (float)a[k] * wself;
                int n32 = deg < 32 ? deg : 32;
                int e = 0;
                for (; e + 4 <= n32; e += 4) {
                    int s0 = __shfl(si, e + 0, 32), s1 = __shfl(si, e + 1, 32);
                    int s2 = __shfl(si, e + 2, 32), s3 = __shfl(si, e + 3, 32);
                    float w0 = __shfl(wi, e + 0, 32), w1 = __shfl(wi, e + 1, 32);
                    float w2 = __shfl(wi, e + 2, 32), w3 = __shfl(wi, e + 3, 32);
                    f16x8 u0 = reinterpret_cast<const f16x8*>(x16 + (size_t)s0 * 256)[l];
                    f16x8 u1 = reinterpret_cast<const f16x8*>(x16 + (size_t)s1 * 256)[l];
                    f16x8 u2 = reinterpret_cast<const f16x8*>(x16 + (size_t)s2 * 256)[l];
                    f16x8 u3 = reinterpret_cast<const f16x8*>(x16 + (size_t)s3 * 256)[l];
                    #pragma unroll
                    for (int k = 0; k < 8; ++k)
                        av[k] += (float)u0[k] * w0 + (float)u1[k] * w1
                               + (float)u2[k] * w2 + (float)u3[k] * w3;
                }
                for (; e < n32; ++e) {
                    int s0 = __shfl(si, e, 32);
                    float w0 = __shfl(wi, e, 32);
                    f16x8 u0 = reinterpret_cast<const f16x8*>(x16 + (size_t)s0 * 256)[l];
                    #pragma unroll
                    for (int k = 0; k < 8; ++k) av[k] += (float)u0[k] * w0;
                }
                for (int e2 = r0 + 32; e2 < r1; ++e2) {       // deg>32 tail (rare)
                    int2 pr = e_pairs[e2];
                    float w0 = __int_as_float(pr.y);
                    f16x8 u0 = reinterpret_cast<const f16x8*>(x16 + (size_t)pr.x * 256)[l];
                    #pragma unroll
                    for (int k = 0; k < 8; ++k) av[k] += (float)u0[k] * w0;
                }
            } else {
                #pragma unroll
                for (int k = 0; k < 8; ++k) av[k] = 0.f;
            }
            f16x8 r;
            #pragma unroll
            for (int k = 0; k < 8; ++k) r[k] = (f16)av[k];
            int slot = (l & 3) ^ ((row >> 1) & 3);
            *reinterpret_cast<f16x8*>(P + (l >> 2) * 2048 + row * 32 + slot * 8) = r;
        }
    }
    __syncthreads();

    // ---- phase 2: h = relu(P @ W1 + b1) — A from LDS, B from L2 ----
    const int wn = tid >> 6;                 // wave = 64-col slice of h
    const int r15 = lane & 15, g = lane >> 4;
    f32x4 acc[4][4] = {};
    for (int step = 0; step < 8; ++step) {
        f16x8 af[4], bf[4];
        #pragma unroll
        for (int mf = 0; mf < 4; ++mf) {
            int row = mf * 16 + r15;
            int slot = g ^ ((row >> 1) & 3);
            af[mf] = *reinterpret_cast<const f16x8*>(P + step * 2048 + row * 32 + slot * 8);
        }
        #pragma unroll
        for (int nf = 0; nf < 4; ++nf) {
            int n1 = wn * 64 + nf * 16 + r15;
            bf[nf] = *reinterpret_cast<const f16x8*>(W1T + (size_t)n1 * 256 + step * 32 + g * 8);
        }
        #pragma unroll
        for (int mf = 0; mf < 4; ++mf)
            #pragma unroll
            for (int nf = 0; nf < 4; ++nf)
                acc[mf][nf] = __builtin_amdgcn_mfma_f32_16x16x32_f16(af[mf], bf[nf], acc[mf][nf], 0, 0, 0);
    }
    __syncthreads();   // all waves done reading P

    // relu + bias, write h back into P (same swizzled layout)
    #pragma unroll
    for (int nf = 0; nf < 4; ++nf) {
        int col = wn * 64 + nf * 16 + r15;
        float bv = b1[col];
        int s = col >> 5, gp = (col >> 3) & 3, c7 = col & 7;
        #pragma unroll
        for (int mf = 0; mf < 4; ++mf) {
            #pragma unroll
            for (int rr = 0; rr < 4; ++rr) {
                int row = mf * 16 + g * 4 + rr;
                float v = fmaxf(acc[mf][nf][rr] + bv, 0.f);
                int slot = gp ^ ((row >> 1) & 3);
                P[s * 2048 + row * 32 + slot * 8 + c7] = (f16)v;
            }
        }
    }
    __syncthreads();

    // ---- phase 3: out = h @ W2 — A from LDS, B from L2 ----
    f32x4 acc2[4][2] = {};
    for (int step = 0; step < 8; ++step) {
        f16x8 af[4], bf[2];
        #pragma unroll
        for (int mf = 0; mf < 4; ++mf) {
            int row = mf * 16 + r15;
            int slot = g ^ ((row >> 1) & 3);
            af[mf] = *reinterpret_cast<const f16x8*>(P + step * 2048 + row * 32 + slot * 8);
        }
        #pragma unroll
        for (int nf = 0; nf < 2; ++nf) {
            int n2 = wn * 32 + nf * 16 + r15;
            bf[nf] = *reinterpret_cast<const f16x8*>(W2T + (size_t)n2 * 256 + step * 32 + g * 8);
        }
        #pragma unroll
        for (int mf = 0; mf < 4; ++mf)
            #pragma unroll
            for (int nf = 0; nf < 2; ++nf)
                acc2[mf][nf] = __builtin_amdgcn_mfma_f32_16x16x32_f16(af[mf], bf[nf], acc2[mf][nf], 0, 0, 0);
    }

    #pragma unroll
    for (int mf = 0; mf < 4; ++mf) {
        #pragma unroll
        for (int nf = 0; nf < 2; ++nf) {
            int col = wn * 32 + nf * 16 + r15;
            #pragma unroll
            for (int rr = 0; rr < 4; ++rr) {
                int rowg = bm + mf * 16 + g * 4 + rr;
                if (rowg < M)
                    hw2[(size_t)rowg * 128 + col] = (f16)acc2[mf][nf][rr];
            }
        }
    }
}

// ---------------- final gather (D=128, f32 out + bias) -----------------------
__global__ void k_gather128(const f16* __restrict__ f, const float* __restrict__ dis,
                            const int* __restrict__ rowptr, const int2* __restrict__ e_pairs,
                            const float* __restrict__ bias, float* __restrict__ outb, int n) {
    int node = (int)(((long long)blockIdx.x * blockDim.x + threadIdx.x) >> 5);
    int l = threadIdx.x & 31;
    if (node >= n) return;
    float dj = dis[node];
    int r0 = rowptr[node], r1 = rowptr[node + 1];
    int deg = r1 - r0;
    int si = 0; float wi = 0.f;
    if (l < deg) { int2 p = e_pairs[r0 + l]; si = p.x; wi = __int_as_float(p.y); }
    f16x4 a = reinterpret_cast<const f16x4*>(f + (size_t)node * 128)[l];
    float wsf = dj * dj;
    float acc[4];
    #pragma unroll
    for (int k = 0; k < 4; ++k) acc[k] = (float)a[k] * wsf;
    int n32 = deg < 32 ? deg : 32;
    int e = 0;
    for (; e + 4 <= n32; e += 4) {
        int s0 = __shfl(si, e + 0, 32), s1 = __shfl(si, e + 1, 32);
        int s2 = __shfl(si, e + 2, 32), s3 = __shfl(si, e + 3, 32);
        float w0 = __shfl(wi, e + 0, 32), w1 = __shfl(wi, e + 1, 32);
        float w2 = __shfl(wi, e + 2, 32), w3 = __shfl(wi, e + 3, 32);
        f16x4 u0 = reinterpret_cast<const f16x4*>(f + (size_t)s0 * 128)[l];
        f16x4 u1 = reinterpret_cast<const f16x4*>(f + (size_t)s1 * 128)[l];
        f16x4 u2 = reinterpret_cast<const f16x4*>(f + (size_t)s2 * 128)[l];
        f16x4 u3 = reinterpret_cast<const f16x4*>(f + (size_t)s3 * 128)[l];
        #pragma unroll
        for (int k = 0; k < 4; ++k)
            acc[k] += (float)u0[k] * w0 + (float)u1[k] * w1 + (float)u2[k] * w2 + (float)u3[k] * w3;
    }
    for (; e < n32; ++e) {
        int s0 = __shfl(si, e, 32);
        float w0 = __shfl(wi, e, 32);
        f16x4 u0 = reinterpret_cast<const f16x4*>(f + (size_t)s0 * 128)[l];
        #pragma unroll
        for (int k = 0; k < 4; ++k) acc[k] += (float)u0[k] * w0;
    }
    for (int e2 = r0 + 32; e2 < r1; ++e2) {
        int2 p = e_pairs[e2];
        float w0 = __int_as_float(p.y);
        f16x4 u0 = reinterpret_cast<const f16x4*>(f + (size_t)p.x * 128)[l];
        #pragma unroll
        for (int k = 0; k < 4; ++k) acc[k] += (float)u0[k] * w0;
    }
    float4 bb = reinterpret_cast<const float4*>(bias)[l];
    float4 r = make_float4(acc[0] + bb.x, acc[1] + bb.y, acc[2] + bb.z, acc[3] + bb.w);
    reinterpret_cast<float4*>(outb + (size_t)node * 128)[l] = r;
}

extern "C" void kernel_launch(void* const* d_in, const int* in_sizes, int n_in,
                              void* d_out, int out_size, void* d_ws, size_t ws_size,
                              hipStream_t stream) {
    const float* x1  = (const float*)d_in[0];
    const float* x2  = (const float*)d_in[1];
    const float* x3  = (const float*)d_in[2];
    const float* Wp1 = (const float*)d_in[3];
    const float* bp1 = (const float*)d_in[4];
    const float* Wp2 = (const float*)d_in[5];
    const float* bp2 = (const float*)d_in[6];
    const float* Wp3 = (const float*)d_in[7];
    const float* bp3 = (const float*)d_in[8];
    const float* W1  = (const float*)d_in[9];
    const float* b1  = (const float*)d_in[10];
    const float* W2  = (const float*)d_in[11];
    const float* b2  = (const float*)d_in[12];
    const int*   ei  = (const int*)d_in[13];
    const int* src = ei;
    const int* dst = ei + EE;
    float* out = (float*)d_out;

    // workspace (~118 MB)
    char* ws = (char*)d_ws;
    size_t off = 0;
    auto alloc = [&](size_t bytes) {
        char* p = ws + off;
        off += (bytes + 511) & ~(size_t)511;
        return p;
    };
    float* dis    = (float*)alloc((size_t)NT * 4);
    int*   cnt    = (int*)alloc((size_t)NT * 4);
    int*   cursor = (int*)alloc((size_t)NT * 4);
    int*   rowptr = (int*)alloc((size_t)(NT + 1) * 4);
    int*   part   = (int*)alloc(256 * 4);
    int2*  e_pairs= (int2*)alloc((size_t)EE * 8);
    f16*   x16    = (f16*)alloc((size_t)NT * 256 * 2);
    f16*   hw216  = (f16*)alloc((size_t)NT * 128 * 2);
    f16*   xc     = (f16*)alloc((size_t)(NN1 * 128 + NN2 * 256 + NN3 * 64) * 2);
    f16*   Wp1T   = (f16*)alloc((size_t)256 * 128 * 2);
    f16*   Wp2T   = (f16*)alloc((size_t)256 * 256 * 2);
    f16*   Wp3T   = (f16*)alloc((size_t)256 * 64 * 2);
    f16*   W1T    = (f16*)alloc((size_t)256 * 256 * 2);
    f16*   W2T    = (f16*)alloc((size_t)128 * 256 * 2);

    f16* x1c = xc;
    f16* x2c = xc + (size_t)NN1 * 128;
    f16* x3c = xc + (size_t)NN1 * 128 + (size_t)NN2 * 256;

    const int nb = cdiv(NT, 1024);

    // 0) CSR build + dis + per-edge weights
    size_t zspan = (size_t)((char*)rowptr - (char*)cnt);   // zero cnt+cursor
    hipMemsetAsync(cnt, 0, zspan, stream);
    k_hist<<<cdiv(EE, 256), 256, 0, stream>>>(dst, cnt, EE);
    k_scan1<<<nb, 256, 0, stream>>>(cnt, rowptr, part, dis, NT);
    k_scan2<<<1, 256, 0, stream>>>(part, nb);
    k_scan3<<<cdiv(NT, 256), 256, 0, stream>>>(rowptr, part, NT, EE);
    k_fill<<<cdiv(EE, 256), 256, 0, stream>>>(src, dst, dis, rowptr, cursor, e_pairs, EE);

    // 1) dtype prep
    {
        int na4 = NN1 * 128 / 4, nb4 = NN2 * 256 / 4, nc4 = NN3 * 64 / 4;
        k_cvt_all<<<cdiv(na4 + nb4 + nc4, 256), 256, 0, stream>>>(x1, na4, x2, nb4, x3, nc4, xc);
        TArgs t = {Wp1, Wp2, Wp3, W1, W2, Wp1T, Wp2T, Wp3T, W1T, W2T};
        k_transpose_all<<<cdiv(212992, 256), 256, 0, stream>>>(t);
    }

    // 2) projections -> x16 (one packed dispatch)
    {
        P3 p = {x1c, x2c, x3c, Wp1T, Wp2T, Wp3T, bp1, bp2, bp3,
                x16, x16 + (size_t)NN1 * 256, x16 + (size_t)(NN1 + NN2) * 256,
                cdiv(NN1, 128), cdiv(NN2, 128)};
        dim3 g(cdiv(NN1, 128) + cdiv(NN2, 128) + cdiv(NN3, 128), 2);
        k_proj3<<<g, 256, 32768, stream>>>(p);
    }

    // 3) fused: gather(Âx) -> GEMM1+ReLU -> GEMM2 -> hw216
    k_fused<<<cdiv(NT, 64), 256, 0, stream>>>(x16, dis, rowptr, e_pairs,
                                              W1T, b1, W2T, hw216, NT);

    // 4) out = Â hw216 + b2  (f32)
    k_gather128<<<cdiv(NT * 32, 256), 256, 0, stream>>>(hw216, dis, rowptr, e_pairs, b2, out, NT);
}

// Round 10
// 287.616 us; speedup vs baseline: 14.4110x; 1.0773x over previous
//
#include <hip/hip_runtime.h>
#include <cstddef>

#define NT 100000
#define NN1 40000
#define NN2 30000
#define NN3 30000
#define EE 800000

typedef _Float16 f16;
typedef f16 f16x8 __attribute__((ext_vector_type(8)));
typedef f16 f16x4 __attribute__((ext_vector_type(4)));
typedef float f32x4 __attribute__((ext_vector_type(4)));

static inline int cdiv(int a, int b) { return (a + b - 1) / b; }

// async global->LDS, 16B per lane
__device__ __forceinline__ void gload_lds16(const f16* g, f16* l) {
    __builtin_amdgcn_global_load_lds(
        (const __attribute__((address_space(1))) void*)g,
        (__attribute__((address_space(3))) void*)l, 16, 0, 0);
}

// ---------------- CSR build (dst-sorted adjacency) --------------------------
__global__ void k_hist(const int* __restrict__ dst, int* __restrict__ cnt, int e) {
    int i = blockIdx.x * blockDim.x + threadIdx.x;
    if (i < e) atomicAdd(&cnt[dst[i]], 1);
}

__global__ void k_scan1(const int* __restrict__ cnt, int* __restrict__ rowptr,
                        int* __restrict__ part, float* __restrict__ dis, int n) {
    __shared__ int sums[256];
    int b = blockIdx.x, t = threadIdx.x;
    int base = b * 1024 + t * 4;
    int v0 = (base + 0 < n) ? cnt[base + 0] : 0;
    int v1 = (base + 1 < n) ? cnt[base + 1] : 0;
    int v2 = (base + 2 < n) ? cnt[base + 2] : 0;
    int v3 = (base + 3 < n) ? cnt[base + 3] : 0;
    if (base + 0 < n) dis[base + 0] = rsqrtf((float)v0 + 1.0f);
    if (base + 1 < n) dis[base + 1] = rsqrtf((float)v1 + 1.0f);
    if (base + 2 < n) dis[base + 2] = rsqrtf((float)v2 + 1.0f);
    if (base + 3 < n) dis[base + 3] = rsqrtf((float)v3 + 1.0f);
    int tsum = v0 + v1 + v2 + v3;
    sums[t] = tsum;
    __syncthreads();
    for (int off = 1; off < 256; off <<= 1) {
        int y = (t >= off) ? sums[t - off] : 0;
        __syncthreads();
        sums[t] += y;
        __syncthreads();
    }
    int excl = sums[t] - tsum;
    if (base + 0 < n) rowptr[base + 0] = excl;
    if (base + 1 < n) rowptr[base + 1] = excl + v0;
    if (base + 2 < n) rowptr[base + 2] = excl + v0 + v1;
    if (base + 3 < n) rowptr[base + 3] = excl + v0 + v1 + v2;
    if (t == 255) part[b] = sums[255];
}

__global__ void k_scan2(int* __restrict__ part, int nb) {
    __shared__ int sums[256];
    int t = threadIdx.x;
    int v = (t < nb) ? part[t] : 0;
    sums[t] = v;
    __syncthreads();
    for (int off = 1; off < 256; off <<= 1) {
        int y = (t >= off) ? sums[t - off] : 0;
        __syncthreads();
        sums[t] += y;
        __syncthreads();
    }
    if (t < nb) part[t] = sums[t] - v;
}

__global__ void k_scan3(int* __restrict__ rowptr, const int* __restrict__ part,
                        int n, int total) {
    int i = blockIdx.x * blockDim.x + threadIdx.x;
    if (i < n) rowptr[i] += part[i >> 10];
    if (i == 0) rowptr[n] = total;
}

// CSR payload: (src, w=dis[src]*dis[dst])
__global__ void k_fill(const int* __restrict__ src, const int* __restrict__ dst,
                       const float* __restrict__ dis, const int* __restrict__ rowptr,
                       int* __restrict__ cursor, int2* __restrict__ e_pairs, int e) {
    int i = blockIdx.x * blockDim.x + threadIdx.x;
    if (i >= e) return;
    int s = src[i], t = dst[i];
    int pos = atomicAdd(&cursor[t], 1);
    int2 p;
    p.x = s;
    p.y = __float_as_int(dis[s] * dis[t]);
    e_pairs[rowptr[t] + pos] = p;
}

// ---------------- dtype prep (merged) ---------------------------------------
__global__ void k_cvt_all(const float* __restrict__ a, int na4,
                          const float* __restrict__ b, int nb4,
                          const float* __restrict__ c, int nc4,
                          f16* __restrict__ o) {
    int i = blockIdx.x * blockDim.x + threadIdx.x;
    const float* s; int j;
    if (i < na4) { s = a; j = i; }
    else if (i < na4 + nb4) { s = b; j = i - na4; }
    else if (i < na4 + nb4 + nc4) { s = c; j = i - na4 - nb4; }
    else return;
    float4 v = reinterpret_cast<const float4*>(s)[j];
    f16x4 r = {(f16)v.x, (f16)v.y, (f16)v.z, (f16)v.w};
    reinterpret_cast<f16x4*>(o)[i] = r;
}

struct TArgs {
    const float *W0, *W1, *W2, *W3, *W4;
    f16 *T0, *T1, *T2, *T3, *T4;
};
__global__ void k_transpose_all(TArgs t) {
    int i = blockIdx.x * blockDim.x + threadIdx.x;
    const float* W; f16* T; int K, N, j;
    if      (i <  32768) { W = t.W0; T = t.T0; K = 128; N = 256; j = i; }
    else if (i <  98304) { W = t.W1; T = t.T1; K = 256; N = 256; j = i - 32768; }
    else if (i < 114688) { W = t.W2; T = t.T2; K =  64; N = 256; j = i - 98304; }
    else if (i < 180224) { W = t.W3; T = t.T3; K = 256; N = 256; j = i - 114688; }
    else if (i < 212992) { W = t.W4; T = t.T4; K = 256; N = 128; j = i - 180224; }
    else return;
    int k = j / N, n = j - k * N;
    T[n * K + k] = (f16)W[j];
}

// ---------------- projection GEMM (128x128 tile, gload_lds dbuf) ------------
template<bool RELU_OUT, bool HAS_BIAS>
__device__ __forceinline__
void hgemm_body(f16* As, f16* Bs,
                const f16* __restrict__ A, const f16* __restrict__ BT,
                const float* __restrict__ bias, f16* __restrict__ C,
                int M, int K, int N, int bx, int by) {
    const int tid = threadIdx.x;
    const int lane = tid & 63;
    const int wid = tid >> 6;
    const int wm = wid & 1, wn = wid >> 1;
    const int bm = bx * 128;
    const int bn = by * 128;
    const int r15 = lane & 15, g = lane >> 4;
    const int sr  = lane >> 2;
    const int chs = (lane & 3) ^ ((lane >> 3) & 3);

    auto stage = [&](int buf, int k0) {
        #pragma unroll
        for (int q = 0; q < 2; ++q) {
            int chunk = wid + q * 4;
            int row = chunk * 16 + sr;
            int ga = bm + row; if (ga >= M) ga = M - 1;
            gload_lds16(A  + (size_t)ga * K + k0 + chs * 8, As + buf * 4096 + chunk * 512);
            gload_lds16(BT + (size_t)(bn + row) * K + k0 + chs * 8, Bs + buf * 4096 + chunk * 512);
        }
    };

    f32x4 acc[4][4] = {};
    const int nsteps = K >> 5;
    stage(0, 0);
    __syncthreads();
    int cur = 0;
    for (int step = 0; step < nsteps; ++step) {
        if (step + 1 < nsteps) stage(cur ^ 1, (step + 1) << 5);
        f16x8 af[4], bf[4];
        const int sl = (g ^ ((r15 >> 1) & 3)) * 8;
        #pragma unroll
        for (int mf = 0; mf < 4; ++mf) {
            int row = wm * 64 + mf * 16 + r15;
            af[mf] = *reinterpret_cast<const f16x8*>(As + cur * 4096 + row * 32 + sl);
        }
        #pragma unroll
        for (int nf = 0; nf < 4; ++nf) {
            int row = wn * 64 + nf * 16 + r15;
            bf[nf] = *reinterpret_cast<const f16x8*>(Bs + cur * 4096 + row * 32 + sl);
        }
        #pragma unroll
        for (int mf = 0; mf < 4; ++mf)
            #pragma unroll
            for (int nf = 0; nf < 4; ++nf)
                acc[mf][nf] = __builtin_amdgcn_mfma_f32_16x16x32_f16(af[mf], bf[nf], acc[mf][nf], 0, 0, 0);
        __syncthreads();
        cur ^= 1;
    }

    #pragma unroll
    for (int mf = 0; mf < 4; ++mf) {
        #pragma unroll
        for (int nf = 0; nf < 4; ++nf) {
            int col = bn + wn * 64 + nf * 16 + r15;
            float bv = HAS_BIAS ? bias[col] : 0.f;
            #pragma unroll
            for (int r = 0; r < 4; ++r) {
                int rowg = bm + wm * 64 + mf * 16 + g * 4 + r;
                if (rowg < M) {
                    float v = acc[mf][nf][r] + bv;
                    if (RELU_OUT) v = fmaxf(v, 0.f);
                    C[(size_t)rowg * N + col] = (f16)v;
                }
            }
        }
    }
}

struct P3 {
    const f16 *a1, *a2, *a3, *t1, *t2, *t3;
    const float *b1, *b2, *b3;
    f16 *o1, *o2, *o3;
    int g1, g2;
};
__global__ __launch_bounds__(256) void k_proj3(P3 p) {
    extern __shared__ f16 smem[];
    int bx = blockIdx.x, by = blockIdx.y;
    if (bx < p.g1)
        hgemm_body<false, true>(smem, smem + 8192, p.a1, p.t1, p.b1, p.o1, NN1, 128, 256, bx, by);
    else if (bx < p.g1 + p.g2)
        hgemm_body<false, true>(smem, smem + 8192, p.a2, p.t2, p.b2, p.o2, NN2, 256, 256, bx - p.g1, by);
    else
        hgemm_body<false, true>(smem, smem + 8192, p.a3, p.t3, p.b3, p.o3, NN3, 64, 256, bx - p.g1 - p.g2, by);
}

// ---------------- FUSED: gather(Âx) -> GEMM1+ReLU -> GEMM2 ------------------
// 512 threads (8 waves), 64 dst nodes/block, LDS P = 32KB.
// Phase 1: 16x32-lane groups, 4 rows each (vs 8 before): 2x issue width,
// half the dependent-chain depth -> restores gather parallelism (R9 fix).
// Phases 2/3: 8 waves split N (32-col h-slices, 16-col out-slices).
// P layout: addr = (col>>5)*2048 + row*32 + slot*8 + (col&7),
//           slot = ((col>>3)&3) ^ ((row>>1)&3).
__global__ __launch_bounds__(512)
void k_fused(const f16* __restrict__ x16, const float* __restrict__ dis,
             const int* __restrict__ rowptr, const int2* __restrict__ e_pairs,
             const f16* __restrict__ W1T, const float* __restrict__ b1,
             const f16* __restrict__ W2T, f16* __restrict__ hw2, int M) {
    __shared__ f16 P[64 * 256];
    const int tid = threadIdx.x;
    const int lane = tid & 63;
    const int bm = blockIdx.x * 64;

    // ---- phase 1: gather 64 agg-rows into P
    {
        const int grp = tid >> 5;     // 0..15
        const int l = tid & 31;
        #pragma unroll
        for (int it = 0; it < 4; ++it) {
            int row = it * 16 + grp;
            int node = bm + row;
            float av[8];
            if (node < M) {
                float dj = dis[node];
                int r0 = rowptr[node], r1 = rowptr[node + 1];
                int deg = r1 - r0;
                int si = 0; float wi = 0.f;
                if (l < deg) { int2 pr = e_pairs[r0 + l]; si = pr.x; wi = __int_as_float(pr.y); }
                f16x8 a = reinterpret_cast<const f16x8*>(x16 + (size_t)node * 256)[l];
                float wself = dj * dj;
                #pragma unroll
                for (int k = 0; k < 8; ++k) av[k] = (float)a[k] * wself;
                int n32 = deg < 32 ? deg : 32;
                int e = 0;
                for (; e + 4 <= n32; e += 4) {
                    int s0 = __shfl(si, e + 0, 32), s1 = __shfl(si, e + 1, 32);
                    int s2 = __shfl(si, e + 2, 32), s3 = __shfl(si, e + 3, 32);
                    float w0 = __shfl(wi, e + 0, 32), w1 = __shfl(wi, e + 1, 32);
                    float w2 = __shfl(wi, e + 2, 32), w3 = __shfl(wi, e + 3, 32);
                    f16x8 u0 = reinterpret_cast<const f16x8*>(x16 + (size_t)s0 * 256)[l];
                    f16x8 u1 = reinterpret_cast<const f16x8*>(x16 + (size_t)s1 * 256)[l];
                    f16x8 u2 = reinterpret_cast<const f16x8*>(x16 + (size_t)s2 * 256)[l];
                    f16x8 u3 = reinterpret_cast<const f16x8*>(x16 + (size_t)s3 * 256)[l];
                    #pragma unroll
                    for (int k = 0; k < 8; ++k)
                        av[k] += (float)u0[k] * w0 + (float)u1[k] * w1
                               + (float)u2[k] * w2 + (float)u3[k] * w3;
                }
                for (; e < n32; ++e) {
                    int s0 = __shfl(si, e, 32);
                    float w0 = __shfl(wi, e, 32);
                    f16x8 u0 = reinterpret_cast<const f16x8*>(x16 + (size_t)s0 * 256)[l];
                    #pragma unroll
                    for (int k = 0; k < 8; ++k) av[k] += (float)u0[k] * w0;
                }
                for (int e2 = r0 + 32; e2 < r1; ++e2) {       // deg>32 tail (rare)
                    int2 pr = e_pairs[e2];
                    float w0 = __int_as_float(pr.y);
                    f16x8 u0 = reinterpret_cast<const f16x8*>(x16 + (size_t)pr.x * 256)[l];
                    #pragma unroll
                    for (int k = 0; k < 8; ++k) av[k] += (float)u0[k] * w0;
                }
            } else {
                #pragma unroll
                for (int k = 0; k < 8; ++k) av[k] = 0.f;
            }
            f16x8 r;
            #pragma unroll
            for (int k = 0; k < 8; ++k) r[k] = (f16)av[k];
            int slot = (l & 3) ^ ((row >> 1) & 3);
            *reinterpret_cast<f16x8*>(P + (l >> 2) * 2048 + row * 32 + slot * 8) = r;
        }
    }
    __syncthreads();

    // ---- phase 2: h = relu(P @ W1 + b1) — wave w owns h cols [w*32, w*32+32)
    const int w = tid >> 6;                  // 0..7
    const int r15 = lane & 15, g = lane >> 4;
    f32x4 acc[4][2] = {};
    for (int step = 0; step < 8; ++step) {
        f16x8 af[4], bf[2];
        #pragma unroll
        for (int mf = 0; mf < 4; ++mf) {
            int row = mf * 16 + r15;
            int slot = g ^ ((row >> 1) & 3);
            af[mf] = *reinterpret_cast<const f16x8*>(P + step * 2048 + row * 32 + slot * 8);
        }
        #pragma unroll
        for (int nf = 0; nf < 2; ++nf) {
            int n1 = w * 32 + nf * 16 + r15;
            bf[nf] = *reinterpret_cast<const f16x8*>(W1T + (size_t)n1 * 256 + step * 32 + g * 8);
        }
        #pragma unroll
        for (int mf = 0; mf < 4; ++mf)
            #pragma unroll
            for (int nf = 0; nf < 2; ++nf)
                acc[mf][nf] = __builtin_amdgcn_mfma_f32_16x16x32_f16(af[mf], bf[nf], acc[mf][nf], 0, 0, 0);
    }
    __syncthreads();   // all waves done reading P

    // relu + bias, write h back into P (same swizzled layout)
    #pragma unroll
    for (int nf = 0; nf < 2; ++nf) {
        int col = w * 32 + nf * 16 + r15;
        float bv = b1[col];
        int gp = (col >> 3) & 3, c7 = col & 7;
        #pragma unroll
        for (int mf = 0; mf < 4; ++mf) {
            #pragma unroll
            for (int rr = 0; rr < 4; ++rr) {
                int row = mf * 16 + g * 4 + rr;
                float v = fmaxf(acc[mf][nf][rr] + bv, 0.f);
                int slot = gp ^ ((row >> 1) & 3);
                P[w * 2048 + row * 32 + slot * 8 + c7] = (f16)v;
            }
        }
    }
    __syncthreads();

    // ---- phase 3: out = h @ W2 — wave w owns out cols [w*16, w*16+16)
    f32x4 acc2[4] = {};
    for (int step = 0; step < 8; ++step) {
        f16x8 af[4], bf;
        #pragma unroll
        for (int mf = 0; mf < 4; ++mf) {
            int row = mf * 16 + r15;
            int slot = g ^ ((row >> 1) & 3);
            af[mf] = *reinterpret_cast<const f16x8*>(P + step * 2048 + row * 32 + slot * 8);
        }
        int n2 = w * 16 + r15;
        bf = *reinterpret_cast<const f16x8*>(W2T + (size_t)n2 * 256 + step * 32 + g * 8);
        #pragma unroll
        for (int mf = 0; mf < 4; ++mf)
            acc2[mf] = __builtin_amdgcn_mfma_f32_16x16x32_f16(af[mf], bf, acc2[mf], 0, 0, 0);
    }

    #pragma unroll
    for (int mf = 0; mf < 4; ++mf) {
        int col = w * 16 + r15;
        #pragma unroll
        for (int rr = 0; rr < 4; ++rr) {
            int rowg = bm + mf * 16 + g * 4 + rr;
            if (rowg < M)
                hw2[(size_t)rowg * 128 + col] = (f16)acc2[mf][rr];
        }
    }
}

// ---------------- final gather (D=128, f32 out + bias) -----------------------
__global__ void k_gather128(const f16* __restrict__ f, const float* __restrict__ dis,
                            const int* __restrict__ rowptr, const int2* __restrict__ e_pairs,
                            const float* __restrict__ bias, float* __restrict__ outb, int n) {
    int node = (int)(((long long)blockIdx.x * blockDim.x + threadIdx.x) >> 5);
    int l = threadIdx.x & 31;
    if (node >= n) return;
    float dj = dis[node];
    int r0 = rowptr[node], r1 = rowptr[node + 1];
    int deg = r1 - r0;
    int si = 0; float wi = 0.f;
    if (l < deg) { int2 p = e_pairs[r0 + l]; si = p.x; wi = __int_as_float(p.y); }
    f16x4 a = reinterpret_cast<const f16x4*>(f + (size_t)node * 128)[l];
    float wsf = dj * dj;
    float acc[4];
    #pragma unroll
    for (int k = 0; k < 4; ++k) acc[k] = (float)a[k] * wsf;
    int n32 = deg < 32 ? deg : 32;
    int e = 0;
    for (; e + 4 <= n32; e += 4) {
        int s0 = __shfl(si, e + 0, 32), s1 = __shfl(si, e + 1, 32);
        int s2 = __shfl(si, e + 2, 32), s3 = __shfl(si, e + 3, 32);
        float w0 = __shfl(wi, e + 0, 32), w1 = __shfl(wi, e + 1, 32);
        float w2 = __shfl(wi, e + 2, 32), w3 = __shfl(wi, e + 3, 32);
        f16x4 u0 = reinterpret_cast<const f16x4*>(f + (size_t)s0 * 128)[l];
        f16x4 u1 = reinterpret_cast<const f16x4*>(f + (size_t)s1 * 128)[l];
        f16x4 u2 = reinterpret_cast<const f16x4*>(f + (size_t)s2 * 128)[l];
        f16x4 u3 = reinterpret_cast<const f16x4*>(f + (size_t)s3 * 128)[l];
        #pragma unroll
        for (int k = 0; k < 4; ++k)
            acc[k] += (float)u0[k] * w0 + (float)u1[k] * w1 + (float)u2[k] * w2 + (float)u3[k] * w3;
    }
    for (; e < n32; ++e) {
        int s0 = __shfl(si, e, 32);
        float w0 = __shfl(wi, e, 32);
        f16x4 u0 = reinterpret_cast<const f16x4*>(f + (size_t)s0 * 128)[l];
        #pragma unroll
        for (int k = 0; k < 4; ++k) acc[k] += (float)u0[k] * w0;
    }
    for (int e2 = r0 + 32; e2 < r1; ++e2) {
        int2 p = e_pairs[e2];
        float w0 = __int_as_float(p.y);
        f16x4 u0 = reinterpret_cast<const f16x4*>(f + (size_t)p.x * 128)[l];
        #pragma unroll
        for (int k = 0; k < 4; ++k) acc[k] += (float)u0[k] * w0;
    }
    float4 bb = reinterpret_cast<const float4*>(bias)[l];
    float4 r = make_float4(acc[0] + bb.x, acc[1] + bb.y, acc[2] + bb.z, acc[3] + bb.w);
    reinterpret_cast<float4*>(outb + (size_t)node * 128)[l] = r;
}

extern "C" void kernel_launch(void* const* d_in, const int* in_sizes, int n_in,
                              void* d_out, int out_size, void* d_ws, size_t ws_size,
                              hipStream_t stream) {
    const float* x1  = (const float*)d_in[0];
    const float* x2  = (const float*)d_in[1];
    const float* x3  = (const float*)d_in[2];
    const float* Wp1 = (const float*)d_in[3];
    const float* bp1 = (const float*)d_in[4];
    const float* Wp2 = (const float*)d_in[5];
    const float* bp2 = (const float*)d_in[6];
    const float* Wp3 = (const float*)d_in[7];
    const float* bp3 = (const float*)d_in[8];
    const float* W1  = (const float*)d_in[9];
    const float* b1  = (const float*)d_in[10];
    const float* W2  = (const float*)d_in[11];
    const float* b2  = (const float*)d_in[12];
    const int*   ei  = (const int*)d_in[13];
    const int* src = ei;
    const int* dst = ei + EE;
    float* out = (float*)d_out;

    // workspace (~118 MB)
    char* ws = (char*)d_ws;
    size_t off = 0;
    auto alloc = [&](size_t bytes) {
        char* p = ws + off;
        off += (bytes + 511) & ~(size_t)511;
        return p;
    };
    float* dis    = (float*)alloc((size_t)NT * 4);
    int*   cnt    = (int*)alloc((size_t)NT * 4);
    int*   cursor = (int*)alloc((size_t)NT * 4);
    int*   rowptr = (int*)alloc((size_t)(NT + 1) * 4);
    int*   part   = (int*)alloc(256 * 4);
    int2*  e_pairs= (int2*)alloc((size_t)EE * 8);
    f16*   x16    = (f16*)alloc((size_t)NT * 256 * 2);
    f16*   hw216  = (f16*)alloc((size_t)NT * 128 * 2);
    f16*   xc     = (f16*)alloc((size_t)(NN1 * 128 + NN2 * 256 + NN3 * 64) * 2);
    f16*   Wp1T   = (f16*)alloc((size_t)256 * 128 * 2);
    f16*   Wp2T   = (f16*)alloc((size_t)256 * 256 * 2);
    f16*   Wp3T   = (f16*)alloc((size_t)256 * 64 * 2);
    f16*   W1T    = (f16*)alloc((size_t)256 * 256 * 2);
    f16*   W2T    = (f16*)alloc((size_t)128 * 256 * 2);

    f16* x1c = xc;
    f16* x2c = xc + (size_t)NN1 * 128;
    f16* x3c = xc + (size_t)NN1 * 128 + (size_t)NN2 * 256;

    const int nb = cdiv(NT, 1024);

    // 0) CSR build + dis + per-edge weights
    size_t zspan = (size_t)((char*)rowptr - (char*)cnt);   // zero cnt+cursor
    hipMemsetAsync(cnt, 0, zspan, stream);
    k_hist<<<cdiv(EE, 256), 256, 0, stream>>>(dst, cnt, EE);
    k_scan1<<<nb, 256, 0, stream>>>(cnt, rowptr, part, dis, NT);
    k_scan2<<<1, 256, 0, stream>>>(part, nb);
    k_scan3<<<cdiv(NT, 256), 256, 0, stream>>>(rowptr, part, NT, EE);
    k_fill<<<cdiv(EE, 256), 256, 0, stream>>>(src, dst, dis, rowptr, cursor, e_pairs, EE);

    // 1) dtype prep
    {
        int na4 = NN1 * 128 / 4, nb4 = NN2 * 256 / 4, nc4 = NN3 * 64 / 4;
        k_cvt_all<<<cdiv(na4 + nb4 + nc4, 256), 256, 0, stream>>>(x1, na4, x2, nb4, x3, nc4, xc);
        TArgs t = {Wp1, Wp2, Wp3, W1, W2, Wp1T, Wp2T, Wp3T, W1T, W2T};
        k_transpose_all<<<cdiv(212992, 256), 256, 0, stream>>>(t);
    }

    // 2) projections -> x16 (one packed dispatch)
    {
        P3 p = {x1c, x2c, x3c, Wp1T, Wp2T, Wp3T, bp1, bp2, bp3,
                x16, x16 + (size_t)NN1 * 256, x16 + (size_t)(NN1 + NN2) * 256,
                cdiv(NN1, 128), cdiv(NN2, 128)};
        dim3 g(cdiv(NN1, 128) + cdiv(NN2, 128) + cdiv(NN3, 128), 2);
        k_proj3<<<g, 256, 32768, stream>>>(p);
    }

    // 3) fused: gather(Âx) -> GEMM1+ReLU -> GEMM2 -> hw216  (512 thr/block)
    k_fused<<<cdiv(NT, 64), 512, 0, stream>>>(x16, dis, rowptr, e_pairs,
                                              W1T, b1, W2T, hw216, NT);

    // 4) out = Â hw216 + b2  (f32)
    k_gather128<<<cdiv(NT * 32, 256), 256, 0, stream>>>(hw216, dis, rowptr, e_pairs, b2, out, NT);
}

// Round 11
// 277.298 us; speedup vs baseline: 14.9472x; 1.0372x over previous
//
#include <hip/hip_runtime.h>
#include <cstddef>

#define NT 100000
#define NN1 40000
#define NN2 30000
#define NN3 30000
#define EE 800000

typedef _Float16 f16;
typedef f16 f16x8 __attribute__((ext_vector_type(8)));
typedef f16 f16x4 __attribute__((ext_vector_type(4)));
typedef float f32x4 __attribute__((ext_vector_type(4)));

static inline int cdiv(int a, int b) { return (a + b - 1) / b; }

// async global->LDS, 16B per lane
__device__ __forceinline__ void gload_lds16(const f16* g, f16* l) {
    __builtin_amdgcn_global_load_lds(
        (const __attribute__((address_space(1))) void*)g,
        (__attribute__((address_space(3))) void*)l, 16, 0, 0);
}

// ---------------- scans ------------------------------------------------------
__global__ void k_scan1(const int* __restrict__ cnt, int* __restrict__ rowptr,
                        int* __restrict__ part, float* __restrict__ dis, int n) {
    __shared__ int sums[256];
    int b = blockIdx.x, t = threadIdx.x;
    int base = b * 1024 + t * 4;
    int v0 = (base + 0 < n) ? cnt[base + 0] : 0;
    int v1 = (base + 1 < n) ? cnt[base + 1] : 0;
    int v2 = (base + 2 < n) ? cnt[base + 2] : 0;
    int v3 = (base + 3 < n) ? cnt[base + 3] : 0;
    if (base + 0 < n) dis[base + 0] = rsqrtf((float)v0 + 1.0f);
    if (base + 1 < n) dis[base + 1] = rsqrtf((float)v1 + 1.0f);
    if (base + 2 < n) dis[base + 2] = rsqrtf((float)v2 + 1.0f);
    if (base + 3 < n) dis[base + 3] = rsqrtf((float)v3 + 1.0f);
    int tsum = v0 + v1 + v2 + v3;
    sums[t] = tsum;
    __syncthreads();
    for (int off = 1; off < 256; off <<= 1) {
        int y = (t >= off) ? sums[t - off] : 0;
        __syncthreads();
        sums[t] += y;
        __syncthreads();
    }
    int excl = sums[t] - tsum;
    if (base + 0 < n) rowptr[base + 0] = excl;
    if (base + 1 < n) rowptr[base + 1] = excl + v0;
    if (base + 2 < n) rowptr[base + 2] = excl + v0 + v1;
    if (base + 3 < n) rowptr[base + 3] = excl + v0 + v1 + v2;
    if (t == 255) part[b] = sums[255];
}

__global__ void k_scan2(int* __restrict__ part, int nb) {
    __shared__ int sums[256];
    int t = threadIdx.x;
    int v = (t < nb) ? part[t] : 0;
    sums[t] = v;
    __syncthreads();
    for (int off = 1; off < 256; off <<= 1) {
        int y = (t >= off) ? sums[t - off] : 0;
        __syncthreads();
        sums[t] += y;
        __syncthreads();
    }
    if (t < nb) part[t] = sums[t] - v;
}

__global__ void k_scan3(int* __restrict__ rowptr, const int* __restrict__ part,
                        int n, int total) {
    int i = blockIdx.x * blockDim.x + threadIdx.x;
    if (i < n) rowptr[i] += part[i >> 10];
    if (i == 0) rowptr[n] = total;
}

// ---------------- merged prep: hist | cvt | transpose ------------------------
struct TArgs {
    const float *W0, *W1, *W2, *W3, *W4;
    f16 *T0, *T1, *T2, *T3, *T4;
};
#define HB   3125     // hist blocks  (EE/256)
#define CVTB 14375    // cvt blocks   ((NN1*128+NN2*256+NN3*64)/4/256)
#define TRB  832      // transpose blocks (212992/256)
#define NA4  1280000
#define NB4  1920000
#define NC4  480000
struct PrepArgs {
    const int* dst; int* cnt;
    const float *x1, *x2, *x3; f16* xc;
    TArgs t;
};
__global__ __launch_bounds__(256) void k_prep(PrepArgs a) {
    int bid = blockIdx.x, tid = threadIdx.x;
    if (bid < HB) {                       // histogram (atomic-bound)
        int i = bid * 256 + tid;
        if (i < EE) atomicAdd(&a.cnt[a.dst[i]], 1);
    } else if (bid < HB + CVTB) {         // f32 -> f16 feature convert
        int i = (bid - HB) * 256 + tid;
        const float* s; int j;
        if (i < NA4) { s = a.x1; j = i; }
        else if (i < NA4 + NB4) { s = a.x2; j = i - NA4; }
        else if (i < NA4 + NB4 + NC4) { s = a.x3; j = i - NA4 - NB4; }
        else return;
        float4 v = reinterpret_cast<const float4*>(s)[j];
        f16x4 r = {(f16)v.x, (f16)v.y, (f16)v.z, (f16)v.w};
        reinterpret_cast<f16x4*>(a.xc)[i] = r;
    } else {                              // weight transpose f32[K][N] -> f16[N][K]
        int i = (bid - HB - CVTB) * 256 + tid;
        const float* W; f16* T; int K, N, j;
        if      (i <  32768) { W = a.t.W0; T = a.t.T0; K = 128; N = 256; j = i; }
        else if (i <  98304) { W = a.t.W1; T = a.t.T1; K = 256; N = 256; j = i - 32768; }
        else if (i < 114688) { W = a.t.W2; T = a.t.T2; K =  64; N = 256; j = i - 98304; }
        else if (i < 180224) { W = a.t.W3; T = a.t.T3; K = 256; N = 256; j = i - 114688; }
        else if (i < 212992) { W = a.t.W4; T = a.t.T4; K = 256; N = 128; j = i - 180224; }
        else return;
        int k = j / N, n = j - k * N;
        T[n * K + k] = (f16)W[j];
    }
}

// ---------------- projection GEMM body (128x128 tile, gload_lds dbuf) -------
template<bool RELU_OUT, bool HAS_BIAS>
__device__ __forceinline__
void hgemm_body(f16* As, f16* Bs,
                const f16* __restrict__ A, const f16* __restrict__ BT,
                const float* __restrict__ bias, f16* __restrict__ C,
                int M, int K, int N, int bx, int by) {
    const int tid = threadIdx.x;
    const int lane = tid & 63;
    const int wid = tid >> 6;
    const int wm = wid & 1, wn = wid >> 1;
    const int bm = bx * 128;
    const int bn = by * 128;
    const int r15 = lane & 15, g = lane >> 4;
    const int sr  = lane >> 2;
    const int chs = (lane & 3) ^ ((lane >> 3) & 3);

    auto stage = [&](int buf, int k0) {
        #pragma unroll
        for (int q = 0; q < 2; ++q) {
            int chunk = wid + q * 4;
            int row = chunk * 16 + sr;
            int ga = bm + row; if (ga >= M) ga = M - 1;
            gload_lds16(A  + (size_t)ga * K + k0 + chs * 8, As + buf * 4096 + chunk * 512);
            gload_lds16(BT + (size_t)(bn + row) * K + k0 + chs * 8, Bs + buf * 4096 + chunk * 512);
        }
    };

    f32x4 acc[4][4] = {};
    const int nsteps = K >> 5;
    stage(0, 0);
    __syncthreads();
    int cur = 0;
    for (int step = 0; step < nsteps; ++step) {
        if (step + 1 < nsteps) stage(cur ^ 1, (step + 1) << 5);
        f16x8 af[4], bf[4];
        const int sl = (g ^ ((r15 >> 1) & 3)) * 8;
        #pragma unroll
        for (int mf = 0; mf < 4; ++mf) {
            int row = wm * 64 + mf * 16 + r15;
            af[mf] = *reinterpret_cast<const f16x8*>(As + cur * 4096 + row * 32 + sl);
        }
        #pragma unroll
        for (int nf = 0; nf < 4; ++nf) {
            int row = wn * 64 + nf * 16 + r15;
            bf[nf] = *reinterpret_cast<const f16x8*>(Bs + cur * 4096 + row * 32 + sl);
        }
        #pragma unroll
        for (int mf = 0; mf < 4; ++mf)
            #pragma unroll
            for (int nf = 0; nf < 4; ++nf)
                acc[mf][nf] = __builtin_amdgcn_mfma_f32_16x16x32_f16(af[mf], bf[nf], acc[mf][nf], 0, 0, 0);
        __syncthreads();
        cur ^= 1;
    }

    #pragma unroll
    for (int mf = 0; mf < 4; ++mf) {
        #pragma unroll
        for (int nf = 0; nf < 4; ++nf) {
            int col = bn + wn * 64 + nf * 16 + r15;
            float bv = HAS_BIAS ? bias[col] : 0.f;
            #pragma unroll
            for (int r = 0; r < 4; ++r) {
                int rowg = bm + wm * 64 + mf * 16 + g * 4 + r;
                if (rowg < M) {
                    float v = acc[mf][nf][r] + bv;
                    if (RELU_OUT) v = fmaxf(v, 0.f);
                    C[(size_t)rowg * N + col] = (f16)v;
                }
            }
        }
    }
}

// ---------------- merged: CSR fill | 3 projections ---------------------------
struct P3 {
    const f16 *a1, *a2, *a3, *t1, *t2, *t3;
    const float *b1, *b2, *b3;
    f16 *o1, *o2, *o3;
    int g1, g2;
};
#define FB 3125    // fill blocks (EE/256)
struct FPArgs {
    const int *src, *dst;
    const float* dis;
    const int* rowptr;
    int* cursor;
    int2* e_pairs;
    P3 p;
};
__global__ __launch_bounds__(256) void k_fillproj(FPArgs a) {
    extern __shared__ f16 smem[];
    int bid = blockIdx.x;
    if (bid < FB) {                        // CSR fill (atomic-bound, hides under MFMA)
        int i = bid * 256 + threadIdx.x;
        if (i >= EE) return;
        int s = a.src[i], t = a.dst[i];
        int pos = atomicAdd(&a.cursor[t], 1);
        int2 pr;
        pr.x = s;
        pr.y = __float_as_int(a.dis[s] * a.dis[t]);
        a.e_pairs[a.rowptr[t] + pos] = pr;
    } else {                               // projections
        int pb = bid - FB;
        int bx = pb >> 1, by = pb & 1;
        if (bx < a.p.g1)
            hgemm_body<false, true>(smem, smem + 8192, a.p.a1, a.p.t1, a.p.b1, a.p.o1, NN1, 128, 256, bx, by);
        else if (bx < a.p.g1 + a.p.g2)
            hgemm_body<false, true>(smem, smem + 8192, a.p.a2, a.p.t2, a.p.b2, a.p.o2, NN2, 256, 256, bx - a.p.g1, by);
        else
            hgemm_body<false, true>(smem, smem + 8192, a.p.a3, a.p.t3, a.p.b3, a.p.o3, NN3, 64, 256, bx - a.p.g1 - a.p.g2, by);
    }
}

// ---------------- FUSED: gather(Âx) -> GEMM1+ReLU -> GEMM2 ------------------
// 512 threads (8 waves), 64 dst nodes/block. Phase-1 edge loop unroll-8:
// 8 independent 512B row-loads in flight per 32-lane group (R10 fix: compiler
// wasn't pipelining unroll-4; VGPR 40 -> ~70, MLP x2).
__global__ __launch_bounds__(512)
void k_fused(const f16* __restrict__ x16, const float* __restrict__ dis,
             const int* __restrict__ rowptr, const int2* __restrict__ e_pairs,
             const f16* __restrict__ W1T, const float* __restrict__ b1,
             const f16* __restrict__ W2T, f16* __restrict__ hw2, int M) {
    __shared__ f16 P[64 * 256];
    const int tid = threadIdx.x;
    const int lane = tid & 63;
    const int bm = blockIdx.x * 64;

    // ---- phase 1: gather 64 agg-rows into P
    {
        const int grp = tid >> 5;     // 0..15
        const int l = tid & 31;
        #pragma unroll
        for (int it = 0; it < 4; ++it) {
            int row = it * 16 + grp;
            int node = bm + row;
            float av[8];
            if (node < M) {
                float dj = dis[node];
                int r0 = rowptr[node], r1 = rowptr[node + 1];
                int deg = r1 - r0;
                int si = 0; float wi = 0.f;
                if (l < deg) { int2 pr = e_pairs[r0 + l]; si = pr.x; wi = __int_as_float(pr.y); }
                f16x8 sa = reinterpret_cast<const f16x8*>(x16 + (size_t)node * 256)[l];
                float wself = dj * dj;
                #pragma unroll
                for (int k = 0; k < 8; ++k) av[k] = (float)sa[k] * wself;
                int n32 = deg < 32 ? deg : 32;
                int e = 0;
                for (; e + 8 <= n32; e += 8) {
                    int s[8]; float w[8];
                    #pragma unroll
                    for (int q = 0; q < 8; ++q) {
                        s[q] = __shfl(si, e + q, 32);
                        w[q] = __shfl(wi, e + q, 32);
                    }
                    f16x8 u[8];
                    #pragma unroll
                    for (int q = 0; q < 8; ++q)
                        u[q] = reinterpret_cast<const f16x8*>(x16 + (size_t)s[q] * 256)[l];
                    #pragma unroll
                    for (int q = 0; q < 8; ++q)
                        #pragma unroll
                        for (int k = 0; k < 8; ++k) av[k] += (float)u[q][k] * w[q];
                }
                for (; e + 4 <= n32; e += 4) {
                    int s[4]; float w[4];
                    #pragma unroll
                    for (int q = 0; q < 4; ++q) {
                        s[q] = __shfl(si, e + q, 32);
                        w[q] = __shfl(wi, e + q, 32);
                    }
                    f16x8 u[4];
                    #pragma unroll
                    for (int q = 0; q < 4; ++q)
                        u[q] = reinterpret_cast<const f16x8*>(x16 + (size_t)s[q] * 256)[l];
                    #pragma unroll
                    for (int q = 0; q < 4; ++q)
                        #pragma unroll
                        for (int k = 0; k < 8; ++k) av[k] += (float)u[q][k] * w[q];
                }
                for (; e < n32; ++e) {
                    int s0 = __shfl(si, e, 32);
                    float w0 = __shfl(wi, e, 32);
                    f16x8 u0 = reinterpret_cast<const f16x8*>(x16 + (size_t)s0 * 256)[l];
                    #pragma unroll
                    for (int k = 0; k < 8; ++k) av[k] += (float)u0[k] * w0;
                }
                for (int e2 = r0 + 32; e2 < r1; ++e2) {       // deg>32 tail (rare)
                    int2 pr = e_pairs[e2];
                    float w0 = __int_as_float(pr.y);
                    f16x8 u0 = reinterpret_cast<const f16x8*>(x16 + (size_t)pr.x * 256)[l];
                    #pragma unroll
                    for (int k = 0; k < 8; ++k) av[k] += (float)u0[k] * w0;
                }
            } else {
                #pragma unroll
                for (int k = 0; k < 8; ++k) av[k] = 0.f;
            }
            f16x8 r;
            #pragma unroll
            for (int k = 0; k < 8; ++k) r[k] = (f16)av[k];
            int slot = (l & 3) ^ ((row >> 1) & 3);
            *reinterpret_cast<f16x8*>(P + (l >> 2) * 2048 + row * 32 + slot * 8) = r;
        }
    }
    __syncthreads();

    // ---- phase 2: h = relu(P @ W1 + b1) — wave w owns h cols [w*32, w*32+32)
    const int w = tid >> 6;
    const int r15 = lane & 15, g = lane >> 4;
    f32x4 acc[4][2] = {};
    for (int step = 0; step < 8; ++step) {
        f16x8 af[4], bf[2];
        #pragma unroll
        for (int mf = 0; mf < 4; ++mf) {
            int row = mf * 16 + r15;
            int slot = g ^ ((row >> 1) & 3);
            af[mf] = *reinterpret_cast<const f16x8*>(P + step * 2048 + row * 32 + slot * 8);
        }
        #pragma unroll
        for (int nf = 0; nf < 2; ++nf) {
            int n1 = w * 32 + nf * 16 + r15;
            bf[nf] = *reinterpret_cast<const f16x8*>(W1T + (size_t)n1 * 256 + step * 32 + g * 8);
        }
        #pragma unroll
        for (int mf = 0; mf < 4; ++mf)
            #pragma unroll
            for (int nf = 0; nf < 2; ++nf)
                acc[mf][nf] = __builtin_amdgcn_mfma_f32_16x16x32_f16(af[mf], bf[nf], acc[mf][nf], 0, 0, 0);
    }
    __syncthreads();

    // relu + bias, write h back into P (same swizzled layout)
    #pragma unroll
    for (int nf = 0; nf < 2; ++nf) {
        int col = w * 32 + nf * 16 + r15;
        float bv = b1[col];
        int gp = (col >> 3) & 3, c7 = col & 7;
        #pragma unroll
        for (int mf = 0; mf < 4; ++mf) {
            #pragma unroll
            for (int rr = 0; rr < 4; ++rr) {
                int row = mf * 16 + g * 4 + rr;
                float v = fmaxf(acc[mf][nf][rr] + bv, 0.f);
                int slot = gp ^ ((row >> 1) & 3);
                P[w * 2048 + row * 32 + slot * 8 + c7] = (f16)v;
            }
        }
    }
    __syncthreads();

    // ---- phase 3: out = h @ W2 — wave w owns out cols [w*16, w*16+16)
    f32x4 acc2[4] = {};
    for (int step = 0; step < 8; ++step) {
        f16x8 af[4], bf;
        #pragma unroll
        for (int mf = 0; mf < 4; ++mf) {
            int row = mf * 16 + r15;
            int slot = g ^ ((row >> 1) & 3);
            af[mf] = *reinterpret_cast<const f16x8*>(P + step * 2048 + row * 32 + slot * 8);
        }
        int n2 = w * 16 + r15;
        bf = *reinterpret_cast<const f16x8*>(W2T + (size_t)n2 * 256 + step * 32 + g * 8);
        #pragma unroll
        for (int mf = 0; mf < 4; ++mf)
            acc2[mf] = __builtin_amdgcn_mfma_f32_16x16x32_f16(af[mf], bf, acc2[mf], 0, 0, 0);
    }

    #pragma unroll
    for (int mf = 0; mf < 4; ++mf) {
        int col = w * 16 + r15;
        #pragma unroll
        for (int rr = 0; rr < 4; ++rr) {
            int rowg = bm + mf * 16 + g * 4 + rr;
            if (rowg < M)
                hw2[(size_t)rowg * 128 + col] = (f16)acc2[mf][rr];
        }
    }
}

// ---------------- final gather (D=128, f32 out + bias, unroll-8) ------------
__global__ void k_gather128(const f16* __restrict__ f, const float* __restrict__ dis,
                            const int* __restrict__ rowptr, const int2* __restrict__ e_pairs,
                            const float* __restrict__ bias, float* __restrict__ outb, int n) {
    int node = (int)(((long long)blockIdx.x * blockDim.x + threadIdx.x) >> 5);
    int l = threadIdx.x & 31;
    if (node >= n) return;
    float dj = dis[node];
    int r0 = rowptr[node], r1 = rowptr[node + 1];
    int deg = r1 - r0;
    int si = 0; float wi = 0.f;
    if (l < deg) { int2 p = e_pairs[r0 + l]; si = p.x; wi = __int_as_float(p.y); }
    f16x4 a = reinterpret_cast<const f16x4*>(f + (size_t)node * 128)[l];
    float wsf = dj * dj;
    float acc[4];
    #pragma unroll
    for (int k = 0; k < 4; ++k) acc[k] = (float)a[k] * wsf;
    int n32 = deg < 32 ? deg : 32;
    int e = 0;
    for (; e + 8 <= n32; e += 8) {
        int s[8]; float w[8];
        #pragma unroll
        for (int q = 0; q < 8; ++q) {
            s[q] = __shfl(si, e + q, 32);
            w[q] = __shfl(wi, e + q, 32);
        }
        f16x4 u[8];
        #pragma unroll
        for (int q = 0; q < 8; ++q)
            u[q] = reinterpret_cast<const f16x4*>(f + (size_t)s[q] * 128)[l];
        #pragma unroll
        for (int q = 0; q < 8; ++q)
            #pragma unroll
            for (int k = 0; k < 4; ++k) acc[k] += (float)u[q][k] * w[q];
    }
    for (; e + 4 <= n32; e += 4) {
        int s[4]; float w[4];
        #pragma unroll
        for (int q = 0; q < 4; ++q) {
            s[q] = __shfl(si, e + q, 32);
            w[q] = __shfl(wi, e + q, 32);
        }
        f16x4 u[4];
        #pragma unroll
        for (int q = 0; q < 4; ++q)
            u[q] = reinterpret_cast<const f16x4*>(f + (size_t)s[q] * 128)[l];
        #pragma unroll
        for (int q = 0; q < 4; ++q)
            #pragma unroll
            for (int k = 0; k < 4; ++k) acc[k] += (float)u[q][k] * w[q];
    }
    for (; e < n32; ++e) {
        int s0 = __shfl(si, e, 32);
        float w0 = __shfl(wi, e, 32);
        f16x4 u0 = reinterpret_cast<const f16x4*>(f + (size_t)s0 * 128)[l];
        #pragma unroll
        for (int k = 0; k < 4; ++k) acc[k] += (float)u0[k] * w0;
    }
    for (int e2 = r0 + 32; e2 < r1; ++e2) {
        int2 p = e_pairs[e2];
        float w0 = __int_as_float(p.y);
        f16x4 u0 = reinterpret_cast<const f16x4*>(f + (size_t)p.x * 128)[l];
        #pragma unroll
        for (int k = 0; k < 4; ++k) acc[k] += (float)u0[k] * w0;
    }
    float4 bb = reinterpret_cast<const float4*>(bias)[l];
    float4 r = make_float4(acc[0] + bb.x, acc[1] + bb.y, acc[2] + bb.z, acc[3] + bb.w);
    reinterpret_cast<float4*>(outb + (size_t)node * 128)[l] = r;
}

extern "C" void kernel_launch(void* const* d_in, const int* in_sizes, int n_in,
                              void* d_out, int out_size, void* d_ws, size_t ws_size,
                              hipStream_t stream) {
    const float* x1  = (const float*)d_in[0];
    const float* x2  = (const float*)d_in[1];
    const float* x3  = (const float*)d_in[2];
    const float* Wp1 = (const float*)d_in[3];
    const float* bp1 = (const float*)d_in[4];
    const float* Wp2 = (const float*)d_in[5];
    const float* bp2 = (const float*)d_in[6];
    const float* Wp3 = (const float*)d_in[7];
    const float* bp3 = (const float*)d_in[8];
    const float* W1  = (const float*)d_in[9];
    const float* b1  = (const float*)d_in[10];
    const float* W2  = (const float*)d_in[11];
    const float* b2  = (const float*)d_in[12];
    const int*   ei  = (const int*)d_in[13];
    const int* src = ei;
    const int* dst = ei + EE;
    float* out = (float*)d_out;

    // workspace (~118 MB)
    char* ws = (char*)d_ws;
    size_t off = 0;
    auto alloc = [&](size_t bytes) {
        char* p = ws + off;
        off += (bytes + 511) & ~(size_t)511;
        return p;
    };
    float* dis    = (float*)alloc((size_t)NT * 4);
    int*   cnt    = (int*)alloc((size_t)NT * 4);
    int*   cursor = (int*)alloc((size_t)NT * 4);
    int*   rowptr = (int*)alloc((size_t)(NT + 1) * 4);
    int*   part   = (int*)alloc(256 * 4);
    int2*  e_pairs= (int2*)alloc((size_t)EE * 8);
    f16*   x16    = (f16*)alloc((size_t)NT * 256 * 2);
    f16*   hw216  = (f16*)alloc((size_t)NT * 128 * 2);
    f16*   xc     = (f16*)alloc((size_t)(NN1 * 128 + NN2 * 256 + NN3 * 64) * 2);
    f16*   Wp1T   = (f16*)alloc((size_t)256 * 128 * 2);
    f16*   Wp2T   = (f16*)alloc((size_t)256 * 256 * 2);
    f16*   Wp3T   = (f16*)alloc((size_t)256 * 64 * 2);
    f16*   W1T    = (f16*)alloc((size_t)256 * 256 * 2);
    f16*   W2T    = (f16*)alloc((size_t)128 * 256 * 2);

    f16* x1c = xc;
    f16* x2c = xc + (size_t)NN1 * 128;
    f16* x3c = xc + (size_t)NN1 * 128 + (size_t)NN2 * 256;

    const int nb = cdiv(NT, 1024);

    // 0) zero cnt+cursor (adjacent allocs)
    size_t zspan = (size_t)((char*)rowptr - (char*)cnt);
    hipMemsetAsync(cnt, 0, zspan, stream);

    // 1) merged prep: hist | cvt | transpose  (independent work co-scheduled)
    {
        PrepArgs a;
        a.dst = dst; a.cnt = cnt;
        a.x1 = x1; a.x2 = x2; a.x3 = x3; a.xc = xc;
        a.t = {Wp1, Wp2, Wp3, W1, W2, Wp1T, Wp2T, Wp3T, W1T, W2T};
        k_prep<<<HB + CVTB + TRB, 256, 0, stream>>>(a);
    }

    // 2) scans (rowptr + dis)
    k_scan1<<<nb, 256, 0, stream>>>(cnt, rowptr, part, dis, NT);
    k_scan2<<<1, 256, 0, stream>>>(part, nb);
    k_scan3<<<cdiv(NT, 256), 256, 0, stream>>>(rowptr, part, NT, EE);

    // 3) merged: CSR fill | projections  (atomics hide under MFMA)
    {
        FPArgs a;
        a.src = src; a.dst = dst; a.dis = dis; a.rowptr = rowptr;
        a.cursor = cursor; a.e_pairs = e_pairs;
        a.p = {x1c, x2c, x3c, Wp1T, Wp2T, Wp3T, bp1, bp2, bp3,
               x16, x16 + (size_t)NN1 * 256, x16 + (size_t)(NN1 + NN2) * 256,
               cdiv(NN1, 128), cdiv(NN2, 128)};
        int projb = (cdiv(NN1, 128) + cdiv(NN2, 128) + cdiv(NN3, 128)) * 2;
        k_fillproj<<<FB + projb, 256, 32768, stream>>>(a);
    }

    // 4) fused: gather(Âx) -> GEMM1+ReLU -> GEMM2 -> hw216
    k_fused<<<cdiv(NT, 64), 512, 0, stream>>>(x16, dis, rowptr, e_pairs,
                                              W1T, b1, W2T, hw216, NT);

    // 5) out = Â hw216 + b2  (f32)
    k_gather128<<<cdiv(NT * 32, 256), 256, 0, stream>>>(hw216, dis, rowptr, e_pairs, b2, out, NT);
}